// Round 1
// baseline (760.906 us; speedup 1.0000x reference)
//
#include <hip/hip_runtime.h>
#include <math.h>

#define BB 4
#define NN 2048
#define DD 512
#define HH 8
#define DH 64
#define MM 256
#define BH 32            // B*H
#define CHK 128
#define NCH 16           // N / CHK
#define ROWS (BH*NN)     // 65536

constexpr float NRM   = 0.35355339059327373f;  // 64^-0.25
constexpr float RATIO = 0.0625f;               // 256^-0.5
constexpr float EPSK  = 1e-4f;
constexpr float EPSD  = 1e-6f;

// workspace offsets (in floats)
#define OFF_QP   ((size_t)0)
#define OFF_KP   (OFF_QP + (size_t)ROWS*MM)            // 16,777,216
#define OFF_S    (OFF_KP + (size_t)ROWS*MM)            // +16,777,216  St layout [bh][tc][e][m]
#define OFF_A    (OFF_S  + (size_t)BH*NCH*MM*DH)       // +8,388,608   A  layout [bh][tc][i][j]
#define OFF_Z    (OFF_A  + (size_t)BH*NCH*CHK*CHK)     // +8,388,608   z  layout [bh][tc][m]
#define OFF_DINV (OFF_Z  + (size_t)BH*NCH*MM)          // +131,072
#define OFF_DINT (OFF_DINV + (size_t)ROWS)             // +65,536
#define OFF_KMP  (OFF_DINT + (size_t)ROWS)             // +65,536
#define OFF_KMAX (OFF_KMP + (size_t)1024)              // +1,024
// total = 50,594,848 floats = ~193 MB

// ---------------------------------------------------------------------------
// Feature kernel: computes data_dash = (x*NRM) @ proj^T for a 64-row block,
// all 256 features. Q mode: subtract per-row max, exp, store qp.
// K mode: store (dash - diag) raw, emit per-block max of raw dash.
// ---------------------------------------------------------------------------
template<bool IS_Q>
__global__ __launch_bounds__(256) void feat_kernel(const float* __restrict__ inp,
                                                   const float* __restrict__ proj,
                                                   float* __restrict__ ws) {
  __shared__ __align__(16) float xs[64][68];     // rows x d (padded)
  __shared__ __align__(16) float ps[128][68];    // proj half x d (padded)
  __shared__ float diag_s[64];
  __shared__ __align__(16) float wmax[64][4];
  __shared__ float kred[4];

  const int t    = threadIdx.x;
  const int w    = t >> 6;       // wave 0..3
  const int lane = t & 63;
  const int mi   = lane & 7;     // feature-group within wave
  const int ri   = lane >> 3;    // row-group 0..7

  const int rowbase = blockIdx.x * 64;
  const int bh = rowbase / NN;
  const int b  = bh / HH, h = bh % HH;
  const int n0 = rowbase % NN;

  // stage x = inp * NRM  (64 rows x 64 d)
  {
    const int r  = t >> 2;
    const int gq = t & 3;
    const float* src = inp + ((size_t)(b*NN + n0 + r))*DD + h*DH;
    #pragma unroll
    for (int j = 0; j < 4; ++j) {
      int g = gq + 4*j;
      float4 v = *(const float4*)(src + g*4);
      v.x *= NRM; v.y *= NRM; v.z *= NRM; v.w *= NRM;
      *(float4*)&xs[r][g*4] = v;
    }
  }
  __syncthreads();
  if (t < 64) {
    float s = 0.f;
    #pragma unroll
    for (int g = 0; g < 16; ++g) {
      float4 v = *(const float4*)&xs[t][g*4];
      s += v.x*v.x + v.y*v.y + v.z*v.z + v.w*v.w;
    }
    diag_s[t] = 0.5f * s;
  }

  float acc[8][8];
  #pragma unroll
  for (int i = 0; i < 8; ++i)
    #pragma unroll
    for (int j = 0; j < 8; ++j) acc[i][j] = 0.f;

  #pragma unroll
  for (int p = 0; p < 2; ++p) {
    __syncthreads();
    // stage proj rows [p*128, p*128+128)
    #pragma unroll
    for (int l = 0; l < 8; ++l) {
      int flat = t + 256*l;
      int r = flat >> 4, g = flat & 15;
      *(float4*)&ps[r][g*4] = *(const float4*)(proj + (size_t)(p*128 + r)*DH + g*4);
    }
    __syncthreads();
    const int mbase = w*32 + mi*4;   // local feature row within this half
    #pragma unroll
    for (int k4 = 0; k4 < 16; ++k4) {
      float4 a4[8];
      #pragma unroll
      for (int ii = 0; ii < 8; ++ii) a4[ii] = *(const float4*)&xs[ri + 8*ii][k4*4];
      #pragma unroll
      for (int jl = 0; jl < 4; ++jl) {
        float4 b4 = *(const float4*)&ps[mbase + jl][k4*4];
        #pragma unroll
        for (int ii = 0; ii < 8; ++ii)
          acc[ii][p*4+jl] += a4[ii].x*b4.x + a4[ii].y*b4.y + a4[ii].z*b4.z + a4[ii].w*b4.w;
      }
    }
  }

  if (IS_Q) {
    // per-row max over this lane's 8 features, reduce across the 8 mi-lanes
    float rmax[8];
    #pragma unroll
    for (int ii = 0; ii < 8; ++ii) {
      float mx = acc[ii][0];
      #pragma unroll
      for (int c = 1; c < 8; ++c) mx = fmaxf(mx, acc[ii][c]);
      mx = fmaxf(mx, __shfl_xor(mx, 1));
      mx = fmaxf(mx, __shfl_xor(mx, 2));
      mx = fmaxf(mx, __shfl_xor(mx, 4));
      rmax[ii] = mx;
    }
    if (mi == 0) {
      #pragma unroll
      for (int ii = 0; ii < 8; ++ii) wmax[ri + 8*ii][w] = rmax[ii];
    }
    __syncthreads();
    float* qp = ws + OFF_QP;
    #pragma unroll
    for (int ii = 0; ii < 8; ++ii) {
      const int r = ri + 8*ii;
      float4 wm4 = *(const float4*)&wmax[r][0];
      const float rm = fmaxf(fmaxf(wm4.x, wm4.y), fmaxf(wm4.z, wm4.w));
      const float dg = diag_s[r];
      float* dst = qp + (size_t)(rowbase + r)*MM;
      #pragma unroll
      for (int p = 0; p < 2; ++p) {
        float4 o;
        o.x = RATIO*(expf(acc[ii][p*4+0] - dg - rm) + EPSK);
        o.y = RATIO*(expf(acc[ii][p*4+1] - dg - rm) + EPSK);
        o.z = RATIO*(expf(acc[ii][p*4+2] - dg - rm) + EPSK);
        o.w = RATIO*(expf(acc[ii][p*4+3] - dg - rm) + EPSK);
        *(float4*)(dst + p*128 + w*32 + mi*4) = o;
      }
    }
  } else {
    // block max of RAW dash (before diag subtraction), matching reference
    float mx = acc[0][0];
    #pragma unroll
    for (int i = 0; i < 8; ++i)
      #pragma unroll
      for (int j = 0; j < 8; ++j) mx = fmaxf(mx, acc[i][j]);
    #pragma unroll
    for (int m = 1; m < 64; m <<= 1) mx = fmaxf(mx, __shfl_xor(mx, m));
    if (lane == 0) kred[w] = mx;
    __syncthreads();
    if (t == 0)
      ws[OFF_KMP + blockIdx.x] = fmaxf(fmaxf(kred[0], kred[1]), fmaxf(kred[2], kred[3]));
    float* kd = ws + OFF_KP;
    #pragma unroll
    for (int ii = 0; ii < 8; ++ii) {
      const int r = ri + 8*ii;
      const float dg = diag_s[r];
      float* dst = kd + (size_t)(rowbase + r)*MM;
      #pragma unroll
      for (int p = 0; p < 2; ++p) {
        float4 o;
        o.x = acc[ii][p*4+0] - dg;
        o.y = acc[ii][p*4+1] - dg;
        o.z = acc[ii][p*4+2] - dg;
        o.w = acc[ii][p*4+3] - dg;
        *(float4*)(dst + p*128 + w*32 + mi*4) = o;
      }
    }
  }
}

// reduce 32 per-bh partial maxes
__global__ void kmax_kernel(float* __restrict__ ws) {
  const int t = threadIdx.x;
  if (t < BH) {
    float m = -1e30f;
    for (int i = 0; i < 32; ++i) m = fmaxf(m, ws[OFF_KMP + t*32 + i]);
    ws[OFF_KMAX + t] = m;
  }
}

// kp = RATIO*(exp(kd - kmax[bh]) + EPSK), in place
__global__ __launch_bounds__(256) void kexp_kernel(float* __restrict__ ws) {
  const size_t i4 = (size_t)blockIdx.x*256 + threadIdx.x;   // < 4,194,304
  const size_t bh = i4 >> 17;                               // 131072 float4 per bh
  const float km = ws[OFF_KMAX + bh];
  float4 v = *(float4*)(ws + OFF_KP + i4*4);
  v.x = RATIO*(expf(v.x - km) + EPSK);
  v.y = RATIO*(expf(v.y - km) + EPSK);
  v.z = RATIO*(expf(v.z - km) + EPSK);
  v.w = RATIO*(expf(v.w - km) + EPSK);
  *(float4*)(ws + OFF_KP + i4*4) = v;
}

// per-chunk G = Kp^T V (stored transposed as St[e][m]) and z colsums
__global__ __launch_bounds__(256) void chunk_sum_kernel(const float* __restrict__ value,
                                                        float* __restrict__ ws) {
  __shared__ __align__(16) float vsh[CHK][DH];   // 32 KB
  const int t = threadIdx.x;                      // == feature m
  const int blk = blockIdx.x;                     // bh*16 + tc
  const int bh = blk >> 4, tc = blk & 15;
  const int b = bh / HH, h = bh % HH;
  const int n0 = tc * CHK;

  #pragma unroll
  for (int l = 0; l < 8; ++l) {
    int flat = t + 256*l;                         // < 2048
    int r = flat >> 4, g = flat & 15;
    *(float4*)&vsh[r][g*4] = *(const float4*)(value + ((size_t)(b*NN + n0 + r))*DD + h*DH + g*4);
  }
  __syncthreads();

  const float* kp = ws + OFF_KP + ((size_t)bh*NN + n0)*MM + t;
  float acc[64];
  #pragma unroll
  for (int e = 0; e < 64; ++e) acc[e] = 0.f;
  float z = 0.f;
  for (int j = 0; j < CHK; ++j) {
    const float kv = kp[(size_t)j*MM];
    z += kv;
    #pragma unroll
    for (int e4 = 0; e4 < 16; ++e4) {
      float4 v4 = *(const float4*)&vsh[j][e4*4];
      acc[e4*4+0] += kv*v4.x; acc[e4*4+1] += kv*v4.y;
      acc[e4*4+2] += kv*v4.z; acc[e4*4+3] += kv*v4.w;
    }
  }
  float* st = ws + OFF_S + (size_t)blk*MM*DH;     // [e][m]
  #pragma unroll
  for (int e = 0; e < 64; ++e) st[(size_t)e*MM + t] = acc[e];
  ws[OFF_Z + (size_t)blk*MM + t] = z;
}

// exclusive prefix over chunks for S (elementwise over 16384 per bh)
__global__ __launch_bounds__(256) void prefix_s_kernel(float* __restrict__ ws) {
  const int bh = blockIdx.x >> 6;
  const int me = ((blockIdx.x & 63) << 8) + threadIdx.x;    // < 16384
  float run = 0.f;
  float* base = ws + OFF_S + (size_t)bh*NCH*MM*DH + me;
  #pragma unroll
  for (int tc = 0; tc < NCH; ++tc) {
    float v = base[(size_t)tc*MM*DH];
    base[(size_t)tc*MM*DH] = run;
    run += v;
  }
}

// exclusive prefix over chunks for z
__global__ __launch_bounds__(256) void prefix_z_kernel(float* __restrict__ ws) {
  const int bh = blockIdx.x;
  const int m  = threadIdx.x;
  float run = 0.f;
  float* base = ws + OFF_Z + (size_t)bh*NCH*MM + m;
  #pragma unroll
  for (int tc = 0; tc < NCH; ++tc) {
    float v = base[(size_t)tc*MM];
    base[(size_t)tc*MM] = run;
    run += v;
  }
}

// A = tril(Qp Kp^T) per chunk + rowsum -> den_intra
__global__ __launch_bounds__(256) void qk_kernel(float* __restrict__ ws) {
  __shared__ __align__(16) float qs[CHK][36];
  __shared__ __align__(16) float ks[CHK][36];
  const int t = threadIdx.x;
  const int blk = blockIdx.x;
  const int bh = blk >> 4, tc = blk & 15;
  const int rowbase = bh*NN + tc*CHK;
  const float* qp = ws + OFF_QP;
  const float* kp = ws + OFF_KP;

  float acc[8][8];
  #pragma unroll
  for (int i = 0; i < 8; ++i)
    #pragma unroll
    for (int j = 0; j < 8; ++j) acc[i][j] = 0.f;

  const int il = t >> 4;   // i = il + 16*ii
  const int jl = t & 15;   // j = jl + 16*jj

  for (int mc = 0; mc < 8; ++mc) {     // K = 256 in chunks of 32
    __syncthreads();
    #pragma unroll
    for (int l = 0; l < 4; ++l) {
      int flat = t + 256*l;            // < 1024 : 128 rows x 8 granules
      int r = flat >> 3, g = flat & 7;
      *(float4*)&qs[r][g*4] = *(const float4*)(qp + (size_t)(rowbase + r)*MM + mc*32 + g*4);
      *(float4*)&ks[r][g*4] = *(const float4*)(kp + (size_t)(rowbase + r)*MM + mc*32 + g*4);
    }
    __syncthreads();
    #pragma unroll
    for (int k4 = 0; k4 < 8; ++k4) {
      float4 a4[8];
      #pragma unroll
      for (int ii = 0; ii < 8; ++ii) a4[ii] = *(const float4*)&qs[il + 16*ii][k4*4];
      #pragma unroll
      for (int jj = 0; jj < 8; ++jj) {
        float4 b4 = *(const float4*)&ks[jl + 16*jj][k4*4];
        #pragma unroll
        for (int ii = 0; ii < 8; ++ii)
          acc[ii][jj] += a4[ii].x*b4.x + a4[ii].y*b4.y + a4[ii].z*b4.z + a4[ii].w*b4.w;
      }
    }
  }

  float* A = ws + OFF_A + (size_t)blk*CHK*CHK;
  #pragma unroll
  for (int ii = 0; ii < 8; ++ii) {
    const int i = il + 16*ii;
    float s = 0.f;
    #pragma unroll
    for (int jj = 0; jj < 8; ++jj) {
      const int j = jl + 16*jj;
      const float v = (j <= i) ? acc[ii][jj] : 0.f;
      A[(size_t)i*CHK + j] = v;
      s += v;
    }
    s += __shfl_xor(s, 1); s += __shfl_xor(s, 2);
    s += __shfl_xor(s, 4); s += __shfl_xor(s, 8);
    if (jl == 0) ws[OFF_DINT + rowbase + i] = s;
  }
}

// den = qp . (z_prev + EPSD) + den_intra ; store 1/den
__global__ __launch_bounds__(256) void den_kernel(float* __restrict__ ws) {
  const int t = threadIdx.x, w = t >> 6, lane = t & 63;
  const int row = blockIdx.x*4 + w;               // < 65536
  const int bh = row >> 11;
  const int nn = row & 2047;
  const int tc = nn >> 7;
  const float4 q4 = *(const float4*)(ws + OFF_QP + (size_t)row*MM + lane*4);
  const float4 z4 = *(const float4*)(ws + OFF_Z + ((size_t)(bh*NCH + tc))*MM + lane*4);
  float s = q4.x*(z4.x+EPSD) + q4.y*(z4.y+EPSD) + q4.z*(z4.z+EPSD) + q4.w*(z4.w+EPSD);
  #pragma unroll
  for (int m = 1; m < 64; m <<= 1) s += __shfl_xor(s, m);
  if (lane == 0) {
    const float den = s + ws[OFF_DINT + row];
    ws[OFF_DINV + row] = 1.0f / den;
  }
}

__device__ __forceinline__ void compute_tile(float (&acc)[8][4],
                                             const float as[][36],
                                             const float bs[][36], int t) {
  const int il = t >> 4, el = t & 15;
  #pragma unroll
  for (int k4 = 0; k4 < 8; ++k4) {
    float4 a4[8];
    #pragma unroll
    for (int ii = 0; ii < 8; ++ii) a4[ii] = *(const float4*)&as[il + 16*ii][k4*4];
    #pragma unroll
    for (int jj = 0; jj < 4; ++jj) {
      float4 b4 = *(const float4*)&bs[el + 16*jj][k4*4];
      #pragma unroll
      for (int ii = 0; ii < 8; ++ii)
        acc[ii][jj] += a4[ii].x*b4.x + a4[ii].y*b4.y + a4[ii].z*b4.z + a4[ii].w*b4.w;
    }
  }
}

// out = (tril(A) @ V + Qp @ S_prev) * dinv
__global__ __launch_bounds__(256) void out_kernel(const float* __restrict__ value,
                                                  float* __restrict__ out,
                                                  float* __restrict__ ws) {
  __shared__ __align__(16) float as[CHK][36];
  __shared__ __align__(16) float bs[DH][36];
  const int t = threadIdx.x;
  const int blk = blockIdx.x;
  const int bh = blk >> 4, tc = blk & 15;
  const int b = bh / HH, h = bh % HH;
  const int n0 = tc*CHK;
  const int rowbase = bh*NN + n0;

  float acc[8][4];
  #pragma unroll
  for (int i = 0; i < 8; ++i)
    #pragma unroll
    for (int j = 0; j < 4; ++j) acc[i][j] = 0.f;

  // phase 1: A @ V, K = 128 in chunks of 32 (V transposed on staging)
  const float* A = ws + OFF_A + (size_t)blk*CHK*CHK;
  for (int kc = 0; kc < 4; ++kc) {
    __syncthreads();
    #pragma unroll
    for (int l = 0; l < 4; ++l) {
      int flat = t + 256*l; int r = flat >> 3, g = flat & 7;
      *(float4*)&as[r][g*4] = *(const float4*)(A + (size_t)r*CHK + kc*32 + g*4);
    }
    #pragma unroll
    for (int l = 0; l < 2; ++l) {
      int flat = t + 256*l;                       // < 512 : 32 j x 16 e-granules
      int jj = flat >> 4, e4 = flat & 15;
      float4 v = *(const float4*)(value + ((size_t)(b*NN + n0 + kc*32 + jj))*DD + h*DH + e4*4);
      bs[e4*4+0][jj] = v.x; bs[e4*4+1][jj] = v.y;
      bs[e4*4+2][jj] = v.z; bs[e4*4+3][jj] = v.w;
    }
    __syncthreads();
    compute_tile(acc, as, bs, t);
  }

  // phase 2: Qp @ S_prev, K = 256 in chunks of 32 (St already [e][m])
  const float* qp = ws + OFF_QP + (size_t)rowbase*MM;
  const float* st = ws + OFF_S + (size_t)blk*MM*DH;
  for (int mc = 0; mc < 8; ++mc) {
    __syncthreads();
    #pragma unroll
    for (int l = 0; l < 4; ++l) {
      int flat = t + 256*l; int r = flat >> 3, g = flat & 7;
      *(float4*)&as[r][g*4] = *(const float4*)(qp + (size_t)r*MM + mc*32 + g*4);
    }
    #pragma unroll
    for (int l = 0; l < 2; ++l) {
      int flat = t + 256*l;                       // 64 e x 8 granules
      int e = flat >> 3, g = flat & 7;
      *(float4*)&bs[e][g*4] = *(const float4*)(st + (size_t)e*MM + mc*32 + g*4);
    }
    __syncthreads();
    compute_tile(acc, as, bs, t);
  }

  const int il = t >> 4;   // i = il + 16*ii
  const int el = t & 15;   // e = el + 16*jj
  #pragma unroll
  for (int ii = 0; ii < 8; ++ii) {
    const int i = il + 16*ii;
    const float di = ws[OFF_DINV + rowbase + i];
    float* dst = out + ((size_t)(b*NN + n0 + i))*DD + h*DH;
    #pragma unroll
    for (int jj = 0; jj < 4; ++jj)
      dst[el + 16*jj] = acc[ii][jj] * di;
  }
}

extern "C" void kernel_launch(void* const* d_in, const int* in_sizes, int n_in,
                              void* d_out, int out_size, void* d_ws, size_t ws_size,
                              hipStream_t stream) {
  (void)in_sizes; (void)n_in; (void)out_size; (void)ws_size;
  const float* q    = (const float*)d_in[0];
  const float* k    = (const float*)d_in[1];
  const float* v    = (const float*)d_in[2];
  const float* proj = (const float*)d_in[3];
  float* out = (float*)d_out;
  float* ws  = (float*)d_ws;

  feat_kernel<true ><<<1024, 256, 0, stream>>>(q, proj, ws);
  feat_kernel<false><<<1024, 256, 0, stream>>>(k, proj, ws);
  kmax_kernel<<<1, 256, 0, stream>>>(ws);
  kexp_kernel<<<16384, 256, 0, stream>>>(ws);
  chunk_sum_kernel<<<512, 256, 0, stream>>>(v, ws);
  prefix_s_kernel<<<2048, 256, 0, stream>>>(ws);
  prefix_z_kernel<<<BH, 256, 0, stream>>>(ws);
  qk_kernel<<<512, 256, 0, stream>>>(ws);
  den_kernel<<<ROWS/4, 256, 0, stream>>>(ws);
  out_kernel<<<512, 256, 0, stream>>>(v, out, ws);
}

// Round 3
// 420.064 us; speedup vs baseline: 1.8114x; 1.8114x over previous
//
#include <hip/hip_runtime.h>
#include <math.h>

#define BB 4
#define NN 2048
#define DD 512
#define HH 8
#define DH 64
#define MM 256
#define BH 32            // B*H
#define CHK 128
#define NCH 16           // N / CHK
#define ROWS (BH*NN)     // 65536

constexpr float NRM   = 0.35355339059327373f;  // 64^-0.25
constexpr float RATIO = 0.0625f;               // 256^-0.5
constexpr float EPSK  = 1e-4f;
constexpr float EPSD  = 1e-6f;

// ---------------- workspace byte offsets ----------------
// qp bf16 [row][m]                          33,554,432 B
// kdash fp32 [row][m] (dead after kexp)     67,108,864 B
//   -> reused: St fp32 [blk][e][m]          33,554,432 B
//   -> reused: SP bf16 [blk][e][m]          16,777,216 B
// kp bf16 [row][m]                          33,554,432 B
// Vt bf16 [bh][e][n]                         8,388,608 B
// z  fp32 [blk][m]                             524,288 B
// kmp fp32 [1024], kmax fp32 [32]
#define OFFB_QP   ((size_t)0)
#define OFFB_KD   ((size_t)33554432)
#define OFFB_ST   OFFB_KD
#define OFFB_SP   (OFFB_KD + (size_t)33554432)
#define OFFB_KP   (OFFB_KD + (size_t)67108864)
#define OFFB_VT   (OFFB_KP + (size_t)33554432)
#define OFFB_Z    (OFFB_VT + (size_t)8388608)
#define OFFB_KMP  (OFFB_Z  + (size_t)524288)
#define OFFB_KMAX (OFFB_KMP + (size_t)4096)
// total ~142.9 MB

typedef __attribute__((ext_vector_type(8))) short short8;
typedef __attribute__((ext_vector_type(4))) float f32x4;

__device__ __forceinline__ float b2f(ushort u) {
  union { float f; unsigned int i; } x; x.i = ((unsigned int)u) << 16; return x.f;
}
__device__ __forceinline__ ushort f2b(float f) {  // RNE
  unsigned int u = __float_as_uint(f);
  unsigned int r = (u + 0x7FFFu + ((u >> 16) & 1u)) >> 16;
  return (ushort)r;
}

// ---------------------------------------------------------------------------
// Feature kernel: data_dash = (x*NRM) @ proj^T for 64 rows x 256 features.
// Q: subtract per-row max, exp, write qp bf16.
// K: write (dash - diag) fp32 + per-block raw-dash max.
// ---------------------------------------------------------------------------
template<bool IS_Q>
__global__ __launch_bounds__(256) void feat_kernel(const float* __restrict__ inp,
                                                   const float* __restrict__ proj,
                                                   char* __restrict__ ws) {
  __shared__ __align__(16) float xs[64][68];
  __shared__ __align__(16) float ps[128][68];
  __shared__ float diag_s[64];
  __shared__ __align__(16) float wmax[64][4];
  __shared__ float kred[4];

  const int t    = threadIdx.x;
  const int w    = t >> 6;
  const int lane = t & 63;
  const int mi   = lane & 7;
  const int ri   = lane >> 3;

  const int rowbase = blockIdx.x * 64;
  const int bh = rowbase / NN;
  const int b  = bh / HH, h = bh % HH;
  const int n0 = rowbase % NN;

  {
    const int r  = t >> 2;
    const int gq = t & 3;
    const float* src = inp + ((size_t)(b*NN + n0 + r))*DD + h*DH;
    #pragma unroll
    for (int j = 0; j < 4; ++j) {
      int g = gq + 4*j;
      float4 v = *(const float4*)(src + g*4);
      v.x *= NRM; v.y *= NRM; v.z *= NRM; v.w *= NRM;
      *(float4*)&xs[r][g*4] = v;
    }
  }
  __syncthreads();
  if (t < 64) {
    float s = 0.f;
    #pragma unroll
    for (int g = 0; g < 16; ++g) {
      float4 v = *(const float4*)&xs[t][g*4];
      s += v.x*v.x + v.y*v.y + v.z*v.z + v.w*v.w;
    }
    diag_s[t] = 0.5f * s;
  }

  float acc[8][8];
  #pragma unroll
  for (int i = 0; i < 8; ++i)
    #pragma unroll
    for (int j = 0; j < 8; ++j) acc[i][j] = 0.f;

  #pragma unroll
  for (int p = 0; p < 2; ++p) {
    __syncthreads();
    #pragma unroll
    for (int l = 0; l < 8; ++l) {
      int flat = t + 256*l;
      int r = flat >> 4, g = flat & 15;
      *(float4*)&ps[r][g*4] = *(const float4*)(proj + (size_t)(p*128 + r)*DH + g*4);
    }
    __syncthreads();
    const int mbase = w*32 + mi*4;
    #pragma unroll
    for (int k4 = 0; k4 < 16; ++k4) {
      float4 a4[8];
      #pragma unroll
      for (int ii = 0; ii < 8; ++ii) a4[ii] = *(const float4*)&xs[ri + 8*ii][k4*4];
      #pragma unroll
      for (int jl = 0; jl < 4; ++jl) {
        float4 b4 = *(const float4*)&ps[mbase + jl][k4*4];
        #pragma unroll
        for (int ii = 0; ii < 8; ++ii)
          acc[ii][p*4+jl] += a4[ii].x*b4.x + a4[ii].y*b4.y + a4[ii].z*b4.z + a4[ii].w*b4.w;
      }
    }
  }

  if (IS_Q) {
    float rmax[8];
    #pragma unroll
    for (int ii = 0; ii < 8; ++ii) {
      float mx = acc[ii][0];
      #pragma unroll
      for (int c = 1; c < 8; ++c) mx = fmaxf(mx, acc[ii][c]);
      mx = fmaxf(mx, __shfl_xor(mx, 1));
      mx = fmaxf(mx, __shfl_xor(mx, 2));
      mx = fmaxf(mx, __shfl_xor(mx, 4));
      rmax[ii] = mx;
    }
    if (mi == 0) {
      #pragma unroll
      for (int ii = 0; ii < 8; ++ii) wmax[ri + 8*ii][w] = rmax[ii];
    }
    __syncthreads();
    ushort* qp = (ushort*)(ws + OFFB_QP);
    #pragma unroll
    for (int ii = 0; ii < 8; ++ii) {
      const int r = ri + 8*ii;
      float4 wm4 = *(const float4*)&wmax[r][0];
      const float rm = fmaxf(fmaxf(wm4.x, wm4.y), fmaxf(wm4.z, wm4.w));
      const float dg = diag_s[r];
      ushort* dst = qp + (size_t)(rowbase + r)*MM;
      #pragma unroll
      for (int p = 0; p < 2; ++p) {
        ushort4 o;
        o.x = f2b(RATIO*(expf(acc[ii][p*4+0] - dg - rm) + EPSK));
        o.y = f2b(RATIO*(expf(acc[ii][p*4+1] - dg - rm) + EPSK));
        o.z = f2b(RATIO*(expf(acc[ii][p*4+2] - dg - rm) + EPSK));
        o.w = f2b(RATIO*(expf(acc[ii][p*4+3] - dg - rm) + EPSK));
        *(ushort4*)(dst + p*128 + w*32 + mi*4) = o;
      }
    }
  } else {
    float mx = acc[0][0];
    #pragma unroll
    for (int i = 0; i < 8; ++i)
      #pragma unroll
      for (int j = 0; j < 8; ++j) mx = fmaxf(mx, acc[i][j]);
    #pragma unroll
    for (int m = 1; m < 64; m <<= 1) mx = fmaxf(mx, __shfl_xor(mx, m));
    if (lane == 0) kred[w] = mx;
    __syncthreads();
    if (t == 0)
      ((float*)(ws + OFFB_KMP))[blockIdx.x] = fmaxf(fmaxf(kred[0], kred[1]), fmaxf(kred[2], kred[3]));
    float* kd = (float*)(ws + OFFB_KD);
    #pragma unroll
    for (int ii = 0; ii < 8; ++ii) {
      const int r = ri + 8*ii;
      const float dg = diag_s[r];
      float* dst = kd + (size_t)(rowbase + r)*MM;
      #pragma unroll
      for (int p = 0; p < 2; ++p) {
        float4 o;
        o.x = acc[ii][p*4+0] - dg;
        o.y = acc[ii][p*4+1] - dg;
        o.z = acc[ii][p*4+2] - dg;
        o.w = acc[ii][p*4+3] - dg;
        *(float4*)(dst + p*128 + w*32 + mi*4) = o;
      }
    }
  }
}

__global__ void kmax_kernel(char* __restrict__ ws) {
  const int t = threadIdx.x;
  if (t < BH) {
    const float* kmp = (const float*)(ws + OFFB_KMP);
    float m = -1e30f;
    for (int i = 0; i < 32; ++i) m = fmaxf(m, kmp[t*32 + i]);
    ((float*)(ws + OFFB_KMAX))[t] = m;
  }
}

// kp_bf16 = RATIO*(exp(kdash - kmax[bh]) + EPSK)
__global__ __launch_bounds__(256) void kexp_kernel(char* __restrict__ ws) {
  const size_t i4 = (size_t)blockIdx.x*256 + threadIdx.x;   // 4 elems each
  const size_t bh = i4 >> 17;
  const float km = ((const float*)(ws + OFFB_KMAX))[bh];
  float4 v = *(const float4*)((const float*)(ws + OFFB_KD) + i4*4);
  ushort4 o;
  o.x = f2b(RATIO*(expf(v.x - km) + EPSK));
  o.y = f2b(RATIO*(expf(v.y - km) + EPSK));
  o.z = f2b(RATIO*(expf(v.z - km) + EPSK));
  o.w = f2b(RATIO*(expf(v.w - km) + EPSK));
  *(ushort4*)((ushort*)(ws + OFFB_KP) + i4*4) = o;
}

// Vt[bh][e][n] = bf16(V[b][n][h*64+e])
__global__ __launch_bounds__(256) void vt_kernel(const float* __restrict__ value,
                                                 char* __restrict__ ws) {
  __shared__ __align__(16) float vsh[128][68];
  const int t = threadIdx.x;
  const int bh = blockIdx.x >> 4, nc = blockIdx.x & 15;
  const int b = bh >> 3, h = bh & 7;
  const int n0 = nc * CHK;
  #pragma unroll
  for (int l = 0; l < 8; ++l) {
    int flat = t + 256*l;
    int r = flat >> 4, g = flat & 15;
    *(float4*)&vsh[r][g*4] = *(const float4*)(value + ((size_t)(b*NN + n0 + r))*DD + h*DH + g*4);
  }
  __syncthreads();
  const int e = t & 63, qd = t >> 6;          // qd: n-quarter 0..3
  ushort* vt = (ushort*)(ws + OFFB_VT) + ((size_t)bh*DH + e)*NN + n0 + qd*32;
  #pragma unroll
  for (int p = 0; p < 16; ++p) {
    unsigned int lo = f2b(vsh[qd*32 + 2*p][e]);
    unsigned int hi = f2b(vsh[qd*32 + 2*p + 1][e]);
    ((unsigned int*)vt)[p] = lo | (hi << 16);
  }
}

// per-chunk G = Kp^T V stored as St[blk][e][m] fp32, plus z colsums
__global__ __launch_bounds__(256) void chunk_sum_kernel(const float* __restrict__ value,
                                                        char* __restrict__ ws) {
  __shared__ __align__(16) float vsh[CHK][DH];
  const int t = threadIdx.x;                      // feature m
  const int blk = blockIdx.x;
  const int bh = blk >> 4, tc = blk & 15;
  const int b = bh >> 3, h = bh & 7;
  const int n0 = tc * CHK;

  #pragma unroll
  for (int l = 0; l < 8; ++l) {
    int flat = t + 256*l;
    int r = flat >> 4, g = flat & 15;
    *(float4*)&vsh[r][g*4] = *(const float4*)(value + ((size_t)(b*NN + n0 + r))*DD + h*DH + g*4);
  }
  __syncthreads();

  const ushort* kp = (const ushort*)(ws + OFFB_KP) + ((size_t)bh*NN + n0)*MM + t;
  float acc[64];
  #pragma unroll
  for (int e = 0; e < 64; ++e) acc[e] = 0.f;
  float z = 0.f;
  for (int j = 0; j < CHK; ++j) {
    const float kv = b2f(kp[(size_t)j*MM]);
    z += kv;
    #pragma unroll
    for (int e4 = 0; e4 < 16; ++e4) {
      float4 v4 = *(const float4*)&vsh[j][e4*4];
      acc[e4*4+0] += kv*v4.x; acc[e4*4+1] += kv*v4.y;
      acc[e4*4+2] += kv*v4.z; acc[e4*4+3] += kv*v4.w;
    }
  }
  float* st = (float*)(ws + OFFB_ST) + (size_t)blk*MM*DH;
  #pragma unroll
  for (int e = 0; e < 64; ++e) st[(size_t)e*MM + t] = acc[e];
  ((float*)(ws + OFFB_Z))[(size_t)blk*MM + t] = z;
}

// exclusive chunk-prefix of St (fp32 running sum) -> SP bf16 [blk][e][m]
__global__ __launch_bounds__(256) void prefix_s_kernel(char* __restrict__ ws) {
  const int bh = blockIdx.x >> 6;
  const int me = ((blockIdx.x & 63) << 8) + threadIdx.x;    // < 16384
  const float* st = (const float*)(ws + OFFB_ST) + (size_t)bh*NCH*MM*DH + me;
  ushort*     sp = (ushort*)(ws + OFFB_SP) + (size_t)bh*NCH*MM*DH + me;
  float run = 0.f;
  #pragma unroll
  for (int tc = 0; tc < NCH; ++tc) {
    float v = st[(size_t)tc*MM*DH];
    sp[(size_t)tc*MM*DH] = f2b(run);
    run += v;
  }
}

// exclusive chunk-prefix of z (fp32, in place)
__global__ __launch_bounds__(256) void prefix_z_kernel(char* __restrict__ ws) {
  const int bh = blockIdx.x;
  const int m  = threadIdx.x;
  float* base = (float*)(ws + OFFB_Z) + (size_t)bh*NCH*MM + m;
  float run = 0.f;
  #pragma unroll
  for (int tc = 0; tc < NCH; ++tc) {
    float v = base[(size_t)tc*MM];
    base[(size_t)tc*MM] = run;
    run += v;
  }
}

#define MFMA(a,b,c) __builtin_amdgcn_mfma_f32_16x16x32_bf16(a, b, c, 0, 0, 0)

// ---------------------------------------------------------------------------
// Fused per-chunk kernel: Sc = Qp Kp^T (MFMA, lower-tri tiles only), tril mask
// + rowsum in C-layout regs, den = qp.(z_prev+eps) + rowsum, P->LDS (A-layout),
// out = (P V + Qp S_prev) * 1/den.
// ---------------------------------------------------------------------------
__global__ __launch_bounds__(256) void fused_kernel(float* __restrict__ out,
                                                    char* __restrict__ ws) {
  __shared__ __align__(16) char lds[52224];
  __shared__ float den_i[128];
  __shared__ float dinv_s[128];

  const int t  = threadIdx.x;
  const int w  = t >> 6;
  const int l  = t & 63;
  const int lq = l >> 4;
  const int ln = l & 15;
  const int blk = blockIdx.x;
  const int bh = blk >> 4, tc = blk & 15;
  const int b = bh >> 3, h = bh & 7;
  const size_t rowbase = (size_t)bh*NN + tc*CHK;

  const ushort* qpg = (const ushort*)(ws + OFFB_QP) + rowbase*MM;
  const ushort* kpg = (const ushort*)(ws + OFFB_KP) + rowbase*MM;

  // ---- Phase A: Sc = Qp Kp^T, K=256 in 4 chunks of 64 ----
  ushort* qs = (ushort*)lds;            // [128][72]
  ushort* ks = qs + 128*72;             // [128][72]

  f32x4 acc[2][8];
  #pragma unroll
  for (int mt = 0; mt < 2; ++mt)
    #pragma unroll
    for (int nt = 0; nt < 8; ++nt) acc[mt][nt] = (f32x4){0.f,0.f,0.f,0.f};

  const int ntmax = 2*w + 2;   // lower-triangle tile columns for this wave

  for (int mc = 0; mc < 4; ++mc) {
    __syncthreads();
    #pragma unroll
    for (int ld2 = 0; ld2 < 4; ++ld2) {
      int flat = t + 256*ld2; int r = flat >> 3, g = flat & 7;
      *(short8*)(qs + r*72 + g*8) = *(const short8*)(qpg + (size_t)r*MM + mc*64 + g*8);
      *(short8*)(ks + r*72 + g*8) = *(const short8*)(kpg + (size_t)r*MM + mc*64 + g*8);
    }
    __syncthreads();
    #pragma unroll
    for (int kk = 0; kk < 2; ++kk) {
      short8 af0 = *(const short8*)(qs + (w*32 +      ln)*72 + kk*32 + lq*8);
      short8 af1 = *(const short8*)(qs + (w*32 + 16 + ln)*72 + kk*32 + lq*8);
      #pragma unroll
      for (int nt = 0; nt < 8; ++nt) {
        if (nt < ntmax) {
          short8 bf = *(const short8*)(ks + (nt*16 + ln)*72 + kk*32 + lq*8);
          acc[0][nt] = MFMA(af0, bf, acc[0][nt]);
          acc[1][nt] = MFMA(af1, bf, acc[1][nt]);
        }
      }
    }
  }

  __syncthreads();   // qs/ks dead; lds becomes P + Vts

  ushort* P   = (ushort*)lds;             // [128][136]
  ushort* Vts = (ushort*)(lds + 34816);   // [64][136]

  // ---- mask + rowsum + write P (C-layout -> A-layout via LDS) ----
  float rs[2][4] = {{0,0,0,0},{0,0,0,0}};
  #pragma unroll
  for (int mt = 0; mt < 2; ++mt)
    #pragma unroll
    for (int nt = 0; nt < 8; ++nt)
      #pragma unroll
      for (int reg = 0; reg < 4; ++reg) {
        int i = w*32 + mt*16 + lq*4 + reg;
        int j = nt*16 + ln;
        float v = (j <= i) ? acc[mt][nt][reg] : 0.f;   // skipped tiles are 0 already
        rs[mt][reg] += v;
        P[i*136 + j] = f2b(v);
      }
  #pragma unroll
  for (int mt = 0; mt < 2; ++mt)
    #pragma unroll
    for (int reg = 0; reg < 4; ++reg) {
      float s = rs[mt][reg];
      s += __shfl_xor(s, 1); s += __shfl_xor(s, 2);
      s += __shfl_xor(s, 4); s += __shfl_xor(s, 8);
      if (ln == 0) den_i[w*32 + mt*16 + lq*4 + reg] = s;
    }

  // ---- stage Vt chunk [64][128]: 64 rows x 16 granules = 1024 stores ----
  const ushort* vtg = (const ushort*)(ws + OFFB_VT) + (size_t)bh*DH*NN + tc*CHK;
  #pragma unroll
  for (int ld2 = 0; ld2 < 4; ++ld2) {
    int flat = t + 256*ld2; int e = flat >> 4, g = flat & 15;
    *(short8*)(Vts + e*136 + g*8) = *(const short8*)(vtg + (size_t)e*NN + g*8);
  }
  __syncthreads();

  // ---- denominator: den = qp.(z_prev+eps) + rowsum ----
  {
    const float* zp = (const float*)(ws + OFFB_Z) + (size_t)blk*MM;
    const int r = t >> 1, hf = t & 1;
    const ushort* qrow = qpg + (size_t)r*MM + hf*128;
    float s = 0.f;
    #pragma unroll
    for (int g = 0; g < 16; ++g) {
      short8 qv = *(const short8*)(qrow + g*8);
      const float* zz = zp + hf*128 + g*8;
      #pragma unroll
      for (int x = 0; x < 8; ++x)
        s += b2f((ushort)qv[x]) * (zz[x] + EPSD);
    }
    s += __shfl_xor(s, 1);
    if (hf == 0) dinv_s[r] = 1.0f / (s + den_i[r]);
  }

  // ---- Phase B: out += P @ V  (K=128) ----
  f32x4 oacc[2][4];
  #pragma unroll
  for (int mt = 0; mt < 2; ++mt)
    #pragma unroll
    for (int nt = 0; nt < 4; ++nt) oacc[mt][nt] = (f32x4){0.f,0.f,0.f,0.f};

  #pragma unroll
  for (int kk = 0; kk < 4; ++kk) {
    short8 af0 = *(const short8*)(P + (w*32 +      ln)*136 + kk*32 + lq*8);
    short8 af1 = *(const short8*)(P + (w*32 + 16 + ln)*136 + kk*32 + lq*8);
    #pragma unroll
    for (int nt = 0; nt < 4; ++nt) {
      short8 bf = *(const short8*)(Vts + (nt*16 + ln)*136 + kk*32 + lq*8);
      oacc[0][nt] = MFMA(af0, bf, oacc[0][nt]);
      oacc[1][nt] = MFMA(af1, bf, oacc[1][nt]);
    }
  }
  __syncthreads();   // P/Vts dead; reuse lds for phase C

  // ---- Phase C: out += Qp @ S_prev (K=256) ----
  ushort* qs2 = (ushort*)lds;           // [128][72]
  ushort* ss  = qs2 + 128*72;           // [64][72]
  const ushort* spg = (const ushort*)(ws + OFFB_SP) + (size_t)blk*DH*MM;
  for (int mc = 0; mc < 4; ++mc) {
    if (mc) __syncthreads();
    #pragma unroll
    for (int ld2 = 0; ld2 < 4; ++ld2) {
      int flat = t + 256*ld2; int r = flat >> 3, g = flat & 7;
      *(short8*)(qs2 + r*72 + g*8) = *(const short8*)(qpg + (size_t)r*MM + mc*64 + g*8);
    }
    #pragma unroll
    for (int ld2 = 0; ld2 < 2; ++ld2) {
      int flat = t + 256*ld2; int e = flat >> 3, g = flat & 7;
      *(short8*)(ss + e*72 + g*8) = *(const short8*)(spg + (size_t)e*MM + mc*64 + g*8);
    }
    __syncthreads();
    #pragma unroll
    for (int kk = 0; kk < 2; ++kk) {
      short8 af0 = *(const short8*)(qs2 + (w*32 +      ln)*72 + kk*32 + lq*8);
      short8 af1 = *(const short8*)(qs2 + (w*32 + 16 + ln)*72 + kk*32 + lq*8);
      #pragma unroll
      for (int nt = 0; nt < 4; ++nt) {
        short8 bf = *(const short8*)(ss + (nt*16 + ln)*72 + kk*32 + lq*8);
        oacc[0][nt] = MFMA(af0, bf, oacc[0][nt]);
        oacc[1][nt] = MFMA(af1, bf, oacc[1][nt]);
      }
    }
  }

  // ---- epilogue: scale by 1/den, write out ----
  #pragma unroll
  for (int mt = 0; mt < 2; ++mt)
    #pragma unroll
    for (int reg = 0; reg < 4; ++reg) {
      const int i = w*32 + mt*16 + lq*4 + reg;
      const float di = dinv_s[i];
      float* dst = out + ((size_t)(b*NN) + tc*CHK + i)*DD + h*DH;
      #pragma unroll
      for (int nt = 0; nt < 4; ++nt)
        dst[nt*16 + ln] = oacc[mt][nt][reg] * di;
    }
}

extern "C" void kernel_launch(void* const* d_in, const int* in_sizes, int n_in,
                              void* d_out, int out_size, void* d_ws, size_t ws_size,
                              hipStream_t stream) {
  (void)in_sizes; (void)n_in; (void)out_size; (void)ws_size;
  const float* q    = (const float*)d_in[0];
  const float* k    = (const float*)d_in[1];
  const float* v    = (const float*)d_in[2];
  const float* proj = (const float*)d_in[3];
  float* out = (float*)d_out;
  char*  ws  = (char*)d_ws;

  feat_kernel<true ><<<1024, 256, 0, stream>>>(q, proj, ws);
  feat_kernel<false><<<1024, 256, 0, stream>>>(k, proj, ws);
  kmax_kernel<<<1, 256, 0, stream>>>(ws);
  kexp_kernel<<<16384, 256, 0, stream>>>(ws);
  vt_kernel<<<512, 256, 0, stream>>>(v, ws);
  chunk_sum_kernel<<<512, 256, 0, stream>>>(v, ws);
  prefix_z_kernel<<<BH, 256, 0, stream>>>(ws);
  prefix_s_kernel<<<2048, 256, 0, stream>>>(ws);
  fused_kernel<<<512, 256, 0, stream>>>(out, ws);
}

// Round 4
// 245.985 us; speedup vs baseline: 3.0933x; 1.7077x over previous
//
#include <hip/hip_runtime.h>
#include <math.h>

#define BB 4
#define NN 2048
#define DD 512
#define HH 8
#define DH 64
#define MM 256
#define BH 32            // B*H
#define CHK 128
#define NCH 16           // N / CHK
#define ROWS (BH*NN)     // 65536

constexpr float NRM   = 0.35355339059327373f;  // 64^-0.25
constexpr float RATIO = 0.0625f;               // 256^-0.5
constexpr float EPSK  = 1e-4f;
constexpr float EPSD  = 1e-6f;

// ---------------- workspace byte offsets ----------------
// qp bf16 [row][m]                          33,554,432 B
// (former kdash region, reused:)
//   St fp32 [blk][e][m]                     33,554,432 B
//   SP bf16 [blk][e][m]                     16,777,216 B
// kp bf16 [row][m]                          33,554,432 B
// Vt bf16 [bh][e][n]                         8,388,608 B
// z  fp32 [blk][m]                             524,288 B
// kmp fp32 [1024], kmax fp32 [32]
#define OFFB_QP   ((size_t)0)
#define OFFB_KD   ((size_t)33554432)
#define OFFB_ST   OFFB_KD
#define OFFB_SP   (OFFB_KD + (size_t)33554432)
#define OFFB_KP   (OFFB_KD + (size_t)67108864)
#define OFFB_VT   (OFFB_KP + (size_t)33554432)
#define OFFB_Z    (OFFB_VT + (size_t)8388608)
#define OFFB_KMP  (OFFB_Z  + (size_t)524288)
#define OFFB_KMAX (OFFB_KMP + (size_t)4096)

typedef __attribute__((ext_vector_type(8))) short short8;
typedef __attribute__((ext_vector_type(4))) float f32x4;

__device__ __forceinline__ float b2f(ushort u) {
  union { float f; unsigned int i; } x; x.i = ((unsigned int)u) << 16; return x.f;
}
__device__ __forceinline__ ushort f2b(float f) {  // RNE
  unsigned int u = __float_as_uint(f);
  unsigned int r = (u + 0x7FFFu + ((u >> 16) & 1u)) >> 16;
  return (ushort)r;
}

#define MFMA(a,b,c) __builtin_amdgcn_mfma_f32_16x16x32_bf16(a, b, c, 0, 0, 0)

// ---------------------------------------------------------------------------
// MFMA feature kernel. 64 rows/block, all 256 features.
// dash = (X*NRM) @ proj^T with split-A (X_hi + X_lo) bf16 MFMA, fp32 acc.
// MODE 0 (Q):    per-row max over 256 feats, qp = ratio*(exp(dash-diag-rm)+eps) -> bf16
// MODE 1 (KMAX): per-block max of raw dash -> kmp[blockIdx]
// MODE 2 (KP):   kp = ratio*(exp(dash-diag-kmax[bh])+eps) -> bf16
// ---------------------------------------------------------------------------
template<int MODE>
__global__ __launch_bounds__(256) void featm_kernel(const float* __restrict__ inp,
                                                    const float* __restrict__ proj,
                                                    char* __restrict__ ws) {
  __shared__ __align__(16) char lds[55296];
  __shared__ float diag_s[64];
  __shared__ __align__(16) float wmax[64][4];
  __shared__ float kred[4];

  ushort* xh = (ushort*)lds;            // [64][72] bf16 hi
  ushort* xl = xh + 64*72;              // [64][72] bf16 lo (residual)
  ushort* ps = xl + 64*72;              // [256][72] proj bf16
  ushort* qt = ps;                      // [64][264] output staging (overlaps ps)

  const int t  = threadIdx.x;
  const int w  = t >> 6;
  const int l  = t & 63;
  const int lq = l >> 4;
  const int ln = l & 15;

  const int rowbase = blockIdx.x * 64;
  const int bh = rowbase >> 11;
  const int b  = bh >> 3, h = bh & 7;
  const int n0 = rowbase & (NN - 1);

  // ---- stage X (scaled, hi/lo split) + diag ----
  {
    const int r  = t >> 2;
    const int c0 = (t & 3) * 16;
    const float* src = inp + ((size_t)(b*NN + n0 + r))*DD + h*DH + c0;
    float vv[16];
    #pragma unroll
    for (int j = 0; j < 4; ++j) {
      float4 v = *(const float4*)(src + j*4);
      vv[4*j+0] = v.x*NRM; vv[4*j+1] = v.y*NRM;
      vv[4*j+2] = v.z*NRM; vv[4*j+3] = v.w*NRM;
    }
    float s = 0.f;
    ushort hi[16], lo[16];
    #pragma unroll
    for (int j = 0; j < 16; ++j) {
      s += vv[j]*vv[j];
      hi[j] = f2b(vv[j]);
      lo[j] = f2b(vv[j] - b2f(hi[j]));
    }
    *(short8*)(xh + r*72 + c0)     = *(short8*)&hi[0];
    *(short8*)(xh + r*72 + c0 + 8) = *(short8*)&hi[8];
    *(short8*)(xl + r*72 + c0)     = *(short8*)&lo[0];
    *(short8*)(xl + r*72 + c0 + 8) = *(short8*)&lo[8];
    s += __shfl_xor(s, 1); s += __shfl_xor(s, 2);
    if ((t & 3) == 0) diag_s[r] = 0.5f * s;
  }
  // ---- stage proj bf16 [256][72] ----
  #pragma unroll
  for (int ld = 0; ld < 4; ++ld) {
    int flat = t + 256*ld;             // < 1024
    int r = flat >> 2, c0 = (flat & 3) * 16;
    const float* src = proj + (size_t)r*DH + c0;
    ushort hv[16];
    #pragma unroll
    for (int j = 0; j < 4; ++j) {
      float4 v = *(const float4*)(src + j*4);
      hv[4*j+0] = f2b(v.x); hv[4*j+1] = f2b(v.y);
      hv[4*j+2] = f2b(v.z); hv[4*j+3] = f2b(v.w);
    }
    *(short8*)(ps + r*72 + c0)     = *(short8*)&hv[0];
    *(short8*)(ps + r*72 + c0 + 8) = *(short8*)&hv[8];
  }
  __syncthreads();

  // ---- MFMA: wave w covers features [w*64, w*64+64), all 64 rows ----
  f32x4 acc[4][4];
  #pragma unroll
  for (int mt = 0; mt < 4; ++mt)
    #pragma unroll
    for (int nt = 0; nt < 4; ++nt) acc[mt][nt] = (f32x4){0.f,0.f,0.f,0.f};

  #pragma unroll
  for (int kk = 0; kk < 2; ++kk) {
    short8 ah[4], al[4];
    #pragma unroll
    for (int mt = 0; mt < 4; ++mt) {
      ah[mt] = *(const short8*)(xh + (mt*16 + ln)*72 + kk*32 + lq*8);
      al[mt] = *(const short8*)(xl + (mt*16 + ln)*72 + kk*32 + lq*8);
    }
    #pragma unroll
    for (int nt = 0; nt < 4; ++nt) {
      short8 bf = *(const short8*)(ps + (w*64 + nt*16 + ln)*72 + kk*32 + lq*8);
      #pragma unroll
      for (int mt = 0; mt < 4; ++mt) {
        acc[mt][nt] = MFMA(al[mt], bf, acc[mt][nt]);
        acc[mt][nt] = MFMA(ah[mt], bf, acc[mt][nt]);
      }
    }
  }

  if (MODE == 1) {
    float mx = -1e30f;
    #pragma unroll
    for (int mt = 0; mt < 4; ++mt)
      #pragma unroll
      for (int nt = 0; nt < 4; ++nt)
        #pragma unroll
        for (int reg = 0; reg < 4; ++reg) mx = fmaxf(mx, acc[mt][nt][reg]);
    #pragma unroll
    for (int m = 1; m < 64; m <<= 1) mx = fmaxf(mx, __shfl_xor(mx, m));
    if (l == 0) kred[w] = mx;
    __syncthreads();
    if (t == 0)
      ((float*)(ws + OFFB_KMP))[blockIdx.x] =
        fmaxf(fmaxf(kred[0], kred[1]), fmaxf(kred[2], kred[3]));
    return;
  }

  if (MODE == 0) {
    // per-row max over this wave's 64 features
    #pragma unroll
    for (int mt = 0; mt < 4; ++mt)
      #pragma unroll
      for (int reg = 0; reg < 4; ++reg) {
        float m = acc[mt][0][reg];
        #pragma unroll
        for (int nt = 1; nt < 4; ++nt) m = fmaxf(m, acc[mt][nt][reg]);
        m = fmaxf(m, __shfl_xor(m, 1));
        m = fmaxf(m, __shfl_xor(m, 2));
        m = fmaxf(m, __shfl_xor(m, 4));
        m = fmaxf(m, __shfl_xor(m, 8));
        if (ln == 0) wmax[mt*16 + lq*4 + reg][w] = m;
      }
  }
  __syncthreads();   // wmax ready; ps reads done -> qt region safe

  float km = 0.f;
  if (MODE == 2) km = ((const float*)(ws + OFFB_KMAX))[bh];

  #pragma unroll
  for (int mt = 0; mt < 4; ++mt)
    #pragma unroll
    for (int reg = 0; reg < 4; ++reg) {
      const int row = mt*16 + lq*4 + reg;
      float rm;
      if (MODE == 0) {
        float4 wm4 = *(const float4*)&wmax[row][0];
        rm = fmaxf(fmaxf(wm4.x, wm4.y), fmaxf(wm4.z, wm4.w));
      } else {
        rm = km;
      }
      const float dg = diag_s[row];
      #pragma unroll
      for (int nt = 0; nt < 4; ++nt)
        qt[row*264 + w*64 + nt*16 + ln] =
          f2b(RATIO*(expf(acc[mt][nt][reg] - dg - rm) + EPSK));
    }
  __syncthreads();

  ushort* dstbase = (ushort*)(ws + (MODE == 0 ? OFFB_QP : OFFB_KP)) + (size_t)rowbase*MM;
  #pragma unroll
  for (int ld = 0; ld < 8; ++ld) {
    int flat = t + 256*ld;             // < 2048
    int row = flat >> 5, g = flat & 31;
    *(short8*)(dstbase + (size_t)row*MM + g*8) = *(const short8*)(qt + row*264 + g*8);
  }
}

// reduce 1024 per-block partial maxes -> per-bh max
__global__ void kmax_kernel(char* __restrict__ ws) {
  const int t = threadIdx.x;
  if (t < BH) {
    const float* kmp = (const float*)(ws + OFFB_KMP);
    float m = -1e30f;
    for (int i = 0; i < 32; ++i) m = fmaxf(m, kmp[t*32 + i]);
    ((float*)(ws + OFFB_KMAX))[t] = m;
  }
}

// Vt[bh][e][n] = bf16(V[b][n][h*64+e])
__global__ __launch_bounds__(256) void vt_kernel(const float* __restrict__ value,
                                                 char* __restrict__ ws) {
  __shared__ __align__(16) float vsh[128][68];
  const int t = threadIdx.x;
  const int bh = blockIdx.x >> 4, nc = blockIdx.x & 15;
  const int b = bh >> 3, h = bh & 7;
  const int n0 = nc * CHK;
  #pragma unroll
  for (int l = 0; l < 8; ++l) {
    int flat = t + 256*l;
    int r = flat >> 4, g = flat & 15;
    *(float4*)&vsh[r][g*4] = *(const float4*)(value + ((size_t)(b*NN + n0 + r))*DD + h*DH + g*4);
  }
  __syncthreads();
  const int e = t & 63, qd = t >> 6;
  ushort* vt = (ushort*)(ws + OFFB_VT) + ((size_t)bh*DH + e)*NN + n0 + qd*32;
  #pragma unroll
  for (int p = 0; p < 16; ++p) {
    unsigned int lo = f2b(vsh[qd*32 + 2*p][e]);
    unsigned int hi = f2b(vsh[qd*32 + 2*p + 1][e]);
    ((unsigned int*)vt)[p] = lo | (hi << 16);
  }
}

// per-chunk G = Kp^T V stored as St[blk][e][m] fp32, plus z colsums
__global__ __launch_bounds__(256) void chunk_sum_kernel(const float* __restrict__ value,
                                                        char* __restrict__ ws) {
  __shared__ __align__(16) float vsh[CHK][DH];
  const int t = threadIdx.x;                      // feature m
  const int blk = blockIdx.x;
  const int bh = blk >> 4, tc = blk & 15;
  const int b = bh >> 3, h = bh & 7;
  const int n0 = tc * CHK;

  #pragma unroll
  for (int l = 0; l < 8; ++l) {
    int flat = t + 256*l;
    int r = flat >> 4, g = flat & 15;
    *(float4*)&vsh[r][g*4] = *(const float4*)(value + ((size_t)(b*NN + n0 + r))*DD + h*DH + g*4);
  }
  __syncthreads();

  const ushort* kp = (const ushort*)(ws + OFFB_KP) + ((size_t)bh*NN + n0)*MM + t;
  float acc[64];
  #pragma unroll
  for (int e = 0; e < 64; ++e) acc[e] = 0.f;
  float z = 0.f;
  for (int j = 0; j < CHK; ++j) {
    const float kv = b2f(kp[(size_t)j*MM]);
    z += kv;
    #pragma unroll
    for (int e4 = 0; e4 < 16; ++e4) {
      float4 v4 = *(const float4*)&vsh[j][e4*4];
      acc[e4*4+0] += kv*v4.x; acc[e4*4+1] += kv*v4.y;
      acc[e4*4+2] += kv*v4.z; acc[e4*4+3] += kv*v4.w;
    }
  }
  float* st = (float*)(ws + OFFB_ST) + (size_t)blk*MM*DH;
  #pragma unroll
  for (int e = 0; e < 64; ++e) st[(size_t)e*MM + t] = acc[e];
  ((float*)(ws + OFFB_Z))[(size_t)blk*MM + t] = z;
}

// exclusive chunk-prefix of St (fp32) -> SP bf16 [blk][e][m]
__global__ __launch_bounds__(256) void prefix_s_kernel(char* __restrict__ ws) {
  const int bh = blockIdx.x >> 6;
  const int me = ((blockIdx.x & 63) << 8) + threadIdx.x;    // < 16384
  const float* st = (const float*)(ws + OFFB_ST) + (size_t)bh*NCH*MM*DH + me;
  ushort*     sp = (ushort*)(ws + OFFB_SP) + (size_t)bh*NCH*MM*DH + me;
  float run = 0.f;
  #pragma unroll
  for (int tc = 0; tc < NCH; ++tc) {
    float v = st[(size_t)tc*MM*DH];
    sp[(size_t)tc*MM*DH] = f2b(run);
    run += v;
  }
}

// exclusive chunk-prefix of z (fp32, in place)
__global__ __launch_bounds__(256) void prefix_z_kernel(char* __restrict__ ws) {
  const int bh = blockIdx.x;
  const int m  = threadIdx.x;
  float* base = (float*)(ws + OFFB_Z) + (size_t)bh*NCH*MM + m;
  float run = 0.f;
  #pragma unroll
  for (int tc = 0; tc < NCH; ++tc) {
    float v = base[(size_t)tc*MM];
    base[(size_t)tc*MM] = run;
    run += v;
  }
}

// ---------------------------------------------------------------------------
// Fused per-chunk kernel: Sc = Qp Kp^T (MFMA, lower-tri tiles only), tril mask
// + rowsum in C-layout regs, den = qp.(z_prev+eps) + rowsum, P->LDS (A-layout),
// out = (P V + Qp S_prev) * 1/den.
// ---------------------------------------------------------------------------
__global__ __launch_bounds__(256) void fused_kernel(float* __restrict__ out,
                                                    char* __restrict__ ws) {
  __shared__ __align__(16) char lds[52224];
  __shared__ float den_i[128];
  __shared__ float dinv_s[128];

  const int t  = threadIdx.x;
  const int w  = t >> 6;
  const int l  = t & 63;
  const int lq = l >> 4;
  const int ln = l & 15;
  const int blk = blockIdx.x;
  const int bh = blk >> 4, tc = blk & 15;
  const int b = bh >> 3, h = bh & 7;
  const size_t rowbase = (size_t)bh*NN + tc*CHK;

  const ushort* qpg = (const ushort*)(ws + OFFB_QP) + rowbase*MM;
  const ushort* kpg = (const ushort*)(ws + OFFB_KP) + rowbase*MM;

  // ---- Phase A: Sc = Qp Kp^T, K=256 in 4 chunks of 64 ----
  ushort* qs = (ushort*)lds;            // [128][72]
  ushort* ks = qs + 128*72;             // [128][72]

  f32x4 acc[2][8];
  #pragma unroll
  for (int mt = 0; mt < 2; ++mt)
    #pragma unroll
    for (int nt = 0; nt < 8; ++nt) acc[mt][nt] = (f32x4){0.f,0.f,0.f,0.f};

  const int ntmax = 2*w + 2;

  for (int mc = 0; mc < 4; ++mc) {
    __syncthreads();
    #pragma unroll
    for (int ld2 = 0; ld2 < 4; ++ld2) {
      int flat = t + 256*ld2; int r = flat >> 3, g = flat & 7;
      *(short8*)(qs + r*72 + g*8) = *(const short8*)(qpg + (size_t)r*MM + mc*64 + g*8);
      *(short8*)(ks + r*72 + g*8) = *(const short8*)(kpg + (size_t)r*MM + mc*64 + g*8);
    }
    __syncthreads();
    #pragma unroll
    for (int kk = 0; kk < 2; ++kk) {
      short8 af0 = *(const short8*)(qs + (w*32 +      ln)*72 + kk*32 + lq*8);
      short8 af1 = *(const short8*)(qs + (w*32 + 16 + ln)*72 + kk*32 + lq*8);
      #pragma unroll
      for (int nt = 0; nt < 8; ++nt) {
        if (nt < ntmax) {
          short8 bf = *(const short8*)(ks + (nt*16 + ln)*72 + kk*32 + lq*8);
          acc[0][nt] = MFMA(af0, bf, acc[0][nt]);
          acc[1][nt] = MFMA(af1, bf, acc[1][nt]);
        }
      }
    }
  }

  __syncthreads();

  ushort* P   = (ushort*)lds;             // [128][136]
  ushort* Vts = (ushort*)(lds + 34816);   // [64][136]

  float rs[2][4] = {{0,0,0,0},{0,0,0,0}};
  #pragma unroll
  for (int mt = 0; mt < 2; ++mt)
    #pragma unroll
    for (int nt = 0; nt < 8; ++nt)
      #pragma unroll
      for (int reg = 0; reg < 4; ++reg) {
        int i = w*32 + mt*16 + lq*4 + reg;
        int j = nt*16 + ln;
        float v = (j <= i) ? acc[mt][nt][reg] : 0.f;
        rs[mt][reg] += v;
        P[i*136 + j] = f2b(v);
      }
  #pragma unroll
  for (int mt = 0; mt < 2; ++mt)
    #pragma unroll
    for (int reg = 0; reg < 4; ++reg) {
      float s = rs[mt][reg];
      s += __shfl_xor(s, 1); s += __shfl_xor(s, 2);
      s += __shfl_xor(s, 4); s += __shfl_xor(s, 8);
      if (ln == 0) den_i[w*32 + mt*16 + lq*4 + reg] = s;
    }

  const ushort* vtg = (const ushort*)(ws + OFFB_VT) + (size_t)bh*DH*NN + tc*CHK;
  #pragma unroll
  for (int ld2 = 0; ld2 < 4; ++ld2) {
    int flat = t + 256*ld2; int e = flat >> 4, g = flat & 15;
    *(short8*)(Vts + e*136 + g*8) = *(const short8*)(vtg + (size_t)e*NN + g*8);
  }
  __syncthreads();

  {
    const float* zp = (const float*)(ws + OFFB_Z) + (size_t)blk*MM;
    const int r = t >> 1, hf = t & 1;
    const ushort* qrow = qpg + (size_t)r*MM + hf*128;
    float s = 0.f;
    #pragma unroll
    for (int g = 0; g < 16; ++g) {
      short8 qv = *(const short8*)(qrow + g*8);
      const float* zz = zp + hf*128 + g*8;
      #pragma unroll
      for (int x = 0; x < 8; ++x)
        s += b2f((ushort)qv[x]) * (zz[x] + EPSD);
    }
    s += __shfl_xor(s, 1);
    if (hf == 0) dinv_s[r] = 1.0f / (s + den_i[r]);
  }

  f32x4 oacc[2][4];
  #pragma unroll
  for (int mt = 0; mt < 2; ++mt)
    #pragma unroll
    for (int nt = 0; nt < 4; ++nt) oacc[mt][nt] = (f32x4){0.f,0.f,0.f,0.f};

  #pragma unroll
  for (int kk = 0; kk < 4; ++kk) {
    short8 af0 = *(const short8*)(P + (w*32 +      ln)*136 + kk*32 + lq*8);
    short8 af1 = *(const short8*)(P + (w*32 + 16 + ln)*136 + kk*32 + lq*8);
    #pragma unroll
    for (int nt = 0; nt < 4; ++nt) {
      short8 bf = *(const short8*)(Vts + (nt*16 + ln)*136 + kk*32 + lq*8);
      oacc[0][nt] = MFMA(af0, bf, oacc[0][nt]);
      oacc[1][nt] = MFMA(af1, bf, oacc[1][nt]);
    }
  }
  __syncthreads();

  ushort* qs2 = (ushort*)lds;           // [128][72]
  ushort* ss  = qs2 + 128*72;           // [64][72]
  const ushort* spg = (const ushort*)(ws + OFFB_SP) + (size_t)blk*DH*MM;
  for (int mc = 0; mc < 4; ++mc) {
    if (mc) __syncthreads();
    #pragma unroll
    for (int ld2 = 0; ld2 < 4; ++ld2) {
      int flat = t + 256*ld2; int r = flat >> 3, g = flat & 7;
      *(short8*)(qs2 + r*72 + g*8) = *(const short8*)(qpg + (size_t)r*MM + mc*64 + g*8);
    }
    #pragma unroll
    for (int ld2 = 0; ld2 < 2; ++ld2) {
      int flat = t + 256*ld2; int e = flat >> 3, g = flat & 7;
      *(short8*)(ss + e*72 + g*8) = *(const short8*)(spg + (size_t)e*MM + mc*64 + g*8);
    }
    __syncthreads();
    #pragma unroll
    for (int kk = 0; kk < 2; ++kk) {
      short8 af0 = *(const short8*)(qs2 + (w*32 +      ln)*72 + kk*32 + lq*8);
      short8 af1 = *(const short8*)(qs2 + (w*32 + 16 + ln)*72 + kk*32 + lq*8);
      #pragma unroll
      for (int nt = 0; nt < 4; ++nt) {
        short8 bf = *(const short8*)(ss + (nt*16 + ln)*72 + kk*32 + lq*8);
        oacc[0][nt] = MFMA(af0, bf, oacc[0][nt]);
        oacc[1][nt] = MFMA(af1, bf, oacc[1][nt]);
      }
    }
  }

  #pragma unroll
  for (int mt = 0; mt < 2; ++mt)
    #pragma unroll
    for (int reg = 0; reg < 4; ++reg) {
      const int i = w*32 + mt*16 + lq*4 + reg;
      const float di = dinv_s[i];
      float* dst = out + ((size_t)(b*NN) + tc*CHK + i)*DD + h*DH;
      #pragma unroll
      for (int nt = 0; nt < 4; ++nt)
        dst[nt*16 + ln] = oacc[mt][nt][reg] * di;
    }
}

extern "C" void kernel_launch(void* const* d_in, const int* in_sizes, int n_in,
                              void* d_out, int out_size, void* d_ws, size_t ws_size,
                              hipStream_t stream) {
  (void)in_sizes; (void)n_in; (void)out_size; (void)ws_size;
  const float* q    = (const float*)d_in[0];
  const float* k    = (const float*)d_in[1];
  const float* v    = (const float*)d_in[2];
  const float* proj = (const float*)d_in[3];
  float* out = (float*)d_out;
  char*  ws  = (char*)d_ws;

  featm_kernel<0><<<1024, 256, 0, stream>>>(q, proj, ws);
  featm_kernel<1><<<1024, 256, 0, stream>>>(k, proj, ws);
  kmax_kernel<<<1, 256, 0, stream>>>(ws);
  featm_kernel<2><<<1024, 256, 0, stream>>>(k, proj, ws);
  vt_kernel<<<512, 256, 0, stream>>>(v, ws);
  chunk_sum_kernel<<<512, 256, 0, stream>>>(v, ws);
  prefix_z_kernel<<<BH, 256, 0, stream>>>(ws);
  prefix_s_kernel<<<2048, 256, 0, stream>>>(ws);
  fused_kernel<<<512, 256, 0, stream>>>(out, ws);
}

// Round 5
// 203.794 us; speedup vs baseline: 3.7337x; 1.2070x over previous
//
#include <hip/hip_runtime.h>
#include <math.h>

#define BB 4
#define NN 2048
#define DD 512
#define HH 8
#define DH 64
#define MM 256
#define BH 32            // B*H
#define CHK 128
#define NCH 16           // N / CHK
#define ROWS (BH*NN)     // 65536

constexpr float NRM   = 0.35355339059327373f;  // 64^-0.25
constexpr float RATIO = 0.0625f;               // 256^-0.5
constexpr float EPSK  = 1e-4f;
constexpr float EPSD  = 1e-6f;

// ---------------- workspace byte offsets ----------------
// qp bf16 [row][m]                          33,554,432 B
// SP bf16 [blk][e][m] (exclusive prefix)    16,777,216 B
// kp bf16 [row][m]                          33,554,432 B
// Vt bf16 [bh][e][n]                         8,388,608 B
// z  fp32 [blk][m] (exclusive prefix)          524,288 B
// kmp fp32 [1024], kmax fp32 [32]
#define OFFB_QP   ((size_t)0)
#define OFFB_SP   ((size_t)33554432)
#define OFFB_KP   (OFFB_SP + (size_t)16777216)
#define OFFB_VT   (OFFB_KP + (size_t)33554432)
#define OFFB_Z    (OFFB_VT + (size_t)8388608)
#define OFFB_KMP  (OFFB_Z  + (size_t)524288)
#define OFFB_KMAX (OFFB_KMP + (size_t)4096)

typedef __attribute__((ext_vector_type(8))) short short8;
typedef __attribute__((ext_vector_type(4))) float f32x4;

__device__ __forceinline__ float b2f(ushort u) {
  union { float f; unsigned int i; } x; x.i = ((unsigned int)u) << 16; return x.f;
}
__device__ __forceinline__ ushort f2b(float f) {  // RNE
  unsigned int u = __float_as_uint(f);
  unsigned int r = (u + 0x7FFFu + ((u >> 16) & 1u)) >> 16;
  return (ushort)r;
}

#define MFMA(a,b,c) __builtin_amdgcn_mfma_f32_16x16x32_bf16(a, b, c, 0, 0, 0)

// ---------------------------------------------------------------------------
// MFMA feature kernel. 64 rows/block, all 256 features.
// dash = (X*NRM) @ proj^T with split-A (X_hi + X_lo) bf16 MFMA, fp32 acc.
// MODE 0 (Q):    per-row max, qp = ratio*(exp(dash-diag-rm)+eps) -> bf16
// MODE 1 (KMAX): per-block max of raw dash -> kmp[blockIdx]
// MODE 2 (KP):   kp = ratio*(exp(dash-diag-kmax[bh])+eps) -> bf16
// ---------------------------------------------------------------------------
template<int MODE>
__global__ __launch_bounds__(256) void featm_kernel(const float* __restrict__ inp,
                                                    const float* __restrict__ proj,
                                                    char* __restrict__ ws) {
  __shared__ __align__(16) char lds[55296];
  __shared__ float diag_s[64];
  __shared__ __align__(16) float wmax[64][4];
  __shared__ float kred[4];

  ushort* xh = (ushort*)lds;            // [64][72] bf16 hi
  ushort* xl = xh + 64*72;              // [64][72] bf16 lo (residual)
  ushort* ps = xl + 64*72;              // [256][72] proj bf16
  ushort* qt = ps;                      // [64][264] output staging (overlaps ps)

  const int t  = threadIdx.x;
  const int w  = t >> 6;
  const int l  = t & 63;
  const int lq = l >> 4;
  const int ln = l & 15;

  const int rowbase = blockIdx.x * 64;
  const int bh = rowbase >> 11;
  const int b  = bh >> 3, h = bh & 7;
  const int n0 = rowbase & (NN - 1);

  // ---- stage X (scaled, hi/lo split) + diag ----
  {
    const int r  = t >> 2;
    const int c0 = (t & 3) * 16;
    const float* src = inp + ((size_t)(b*NN + n0 + r))*DD + h*DH + c0;
    float vv[16];
    #pragma unroll
    for (int j = 0; j < 4; ++j) {
      float4 v = *(const float4*)(src + j*4);
      vv[4*j+0] = v.x*NRM; vv[4*j+1] = v.y*NRM;
      vv[4*j+2] = v.z*NRM; vv[4*j+3] = v.w*NRM;
    }
    float s = 0.f;
    ushort hi[16], lo[16];
    #pragma unroll
    for (int j = 0; j < 16; ++j) {
      s += vv[j]*vv[j];
      hi[j] = f2b(vv[j]);
      lo[j] = f2b(vv[j] - b2f(hi[j]));
    }
    *(short8*)(xh + r*72 + c0)     = *(short8*)&hi[0];
    *(short8*)(xh + r*72 + c0 + 8) = *(short8*)&hi[8];
    *(short8*)(xl + r*72 + c0)     = *(short8*)&lo[0];
    *(short8*)(xl + r*72 + c0 + 8) = *(short8*)&lo[8];
    s += __shfl_xor(s, 1); s += __shfl_xor(s, 2);
    if ((t & 3) == 0) diag_s[r] = 0.5f * s;
  }
  // ---- stage proj bf16 [256][72] ----
  #pragma unroll
  for (int ld = 0; ld < 4; ++ld) {
    int flat = t + 256*ld;             // < 1024
    int r = flat >> 2, c0 = (flat & 3) * 16;
    const float* src = proj + (size_t)r*DH + c0;
    ushort hv[16];
    #pragma unroll
    for (int j = 0; j < 4; ++j) {
      float4 v = *(const float4*)(src + j*4);
      hv[4*j+0] = f2b(v.x); hv[4*j+1] = f2b(v.y);
      hv[4*j+2] = f2b(v.z); hv[4*j+3] = f2b(v.w);
    }
    *(short8*)(ps + r*72 + c0)     = *(short8*)&hv[0];
    *(short8*)(ps + r*72 + c0 + 8) = *(short8*)&hv[8];
  }
  __syncthreads();

  // ---- MFMA: wave w covers features [w*64, w*64+64), all 64 rows ----
  f32x4 acc[4][4];
  #pragma unroll
  for (int mt = 0; mt < 4; ++mt)
    #pragma unroll
    for (int nt = 0; nt < 4; ++nt) acc[mt][nt] = (f32x4){0.f,0.f,0.f,0.f};

  #pragma unroll
  for (int kk = 0; kk < 2; ++kk) {
    short8 ah[4], al[4];
    #pragma unroll
    for (int mt = 0; mt < 4; ++mt) {
      ah[mt] = *(const short8*)(xh + (mt*16 + ln)*72 + kk*32 + lq*8);
      al[mt] = *(const short8*)(xl + (mt*16 + ln)*72 + kk*32 + lq*8);
    }
    #pragma unroll
    for (int nt = 0; nt < 4; ++nt) {
      short8 bf = *(const short8*)(ps + (w*64 + nt*16 + ln)*72 + kk*32 + lq*8);
      #pragma unroll
      for (int mt = 0; mt < 4; ++mt) {
        acc[mt][nt] = MFMA(al[mt], bf, acc[mt][nt]);
        acc[mt][nt] = MFMA(ah[mt], bf, acc[mt][nt]);
      }
    }
  }

  if (MODE == 1) {
    float mx = -1e30f;
    #pragma unroll
    for (int mt = 0; mt < 4; ++mt)
      #pragma unroll
      for (int nt = 0; nt < 4; ++nt)
        #pragma unroll
        for (int reg = 0; reg < 4; ++reg) mx = fmaxf(mx, acc[mt][nt][reg]);
    #pragma unroll
    for (int m = 1; m < 64; m <<= 1) mx = fmaxf(mx, __shfl_xor(mx, m));
    if (l == 0) kred[w] = mx;
    __syncthreads();
    if (t == 0)
      ((float*)(ws + OFFB_KMP))[blockIdx.x] =
        fmaxf(fmaxf(kred[0], kred[1]), fmaxf(kred[2], kred[3]));
    return;
  }

  if (MODE == 0) {
    #pragma unroll
    for (int mt = 0; mt < 4; ++mt)
      #pragma unroll
      for (int reg = 0; reg < 4; ++reg) {
        float m = acc[mt][0][reg];
        #pragma unroll
        for (int nt = 1; nt < 4; ++nt) m = fmaxf(m, acc[mt][nt][reg]);
        m = fmaxf(m, __shfl_xor(m, 1));
        m = fmaxf(m, __shfl_xor(m, 2));
        m = fmaxf(m, __shfl_xor(m, 4));
        m = fmaxf(m, __shfl_xor(m, 8));
        if (ln == 0) wmax[mt*16 + lq*4 + reg][w] = m;
      }
  }
  __syncthreads();   // wmax ready; ps reads done -> qt region safe

  float km = 0.f;
  if (MODE == 2) km = ((const float*)(ws + OFFB_KMAX))[bh];

  #pragma unroll
  for (int mt = 0; mt < 4; ++mt)
    #pragma unroll
    for (int reg = 0; reg < 4; ++reg) {
      const int row = mt*16 + lq*4 + reg;
      float rm;
      if (MODE == 0) {
        float4 wm4 = *(const float4*)&wmax[row][0];
        rm = fmaxf(fmaxf(wm4.x, wm4.y), fmaxf(wm4.z, wm4.w));
      } else {
        rm = km;
      }
      const float dg = diag_s[row];
      #pragma unroll
      for (int nt = 0; nt < 4; ++nt)
        qt[row*264 + w*64 + nt*16 + ln] =
          f2b(RATIO*(expf(acc[mt][nt][reg] - dg - rm) + EPSK));
    }
  __syncthreads();

  ushort* dstbase = (ushort*)(ws + (MODE == 0 ? OFFB_QP : OFFB_KP)) + (size_t)rowbase*MM;
  #pragma unroll
  for (int ld = 0; ld < 8; ++ld) {
    int flat = t + 256*ld;             // < 2048
    int row = flat >> 5, g = flat & 31;
    *(short8*)(dstbase + (size_t)row*MM + g*8) = *(const short8*)(qt + row*264 + g*8);
  }
}

// reduce 1024 per-block partial maxes -> per-bh max
__global__ void kmax_kernel(char* __restrict__ ws) {
  const int t = threadIdx.x;
  if (t < BH) {
    const float* kmp = (const float*)(ws + OFFB_KMP);
    float m = -1e30f;
    for (int i = 0; i < 32; ++i) m = fmaxf(m, kmp[t*32 + i]);
    ((float*)(ws + OFFB_KMAX))[t] = m;
  }
}

// Vt[bh][e][n] = bf16(V[b][n][h*64+e])
__global__ __launch_bounds__(256) void vt_kernel(const float* __restrict__ value,
                                                 char* __restrict__ ws) {
  __shared__ __align__(16) float vsh[128][68];
  const int t = threadIdx.x;
  const int bh = blockIdx.x >> 4, nc = blockIdx.x & 15;
  const int b = bh >> 3, h = bh & 7;
  const int n0 = nc * CHK;
  #pragma unroll
  for (int l = 0; l < 8; ++l) {
    int flat = t + 256*l;
    int r = flat >> 4, g = flat & 15;
    *(float4*)&vsh[r][g*4] = *(const float4*)(value + ((size_t)(b*NN + n0 + r))*DD + h*DH + g*4);
  }
  __syncthreads();
  const int e = t & 63, qd = t >> 6;
  ushort* vt = (ushort*)(ws + OFFB_VT) + ((size_t)bh*DH + e)*NN + n0 + qd*32;
  #pragma unroll
  for (int p = 0; p < 16; ++p) {
    unsigned int lo = f2b(vsh[qd*32 + 2*p][e]);
    unsigned int hi = f2b(vsh[qd*32 + 2*p + 1][e]);
    ((unsigned int*)vt)[p] = lo | (hi << 16);
  }
}

// ---------------------------------------------------------------------------
// MFMA chunk-scan: per (bh, 64-feature slice), sequentially over 16 chunks:
//   write exclusive-prefix acc -> SP bf16 / zrun -> Z, then
//   acc += G_tc = Vt_chunk (A, [e][k]) x kpT_chunk (B, [m][k]) via MFMA.
// Replaces chunk_sum + prefix_s + prefix_z; St fp32 eliminated.
// ---------------------------------------------------------------------------
__global__ __launch_bounds__(256) void sprefix_kernel(char* __restrict__ ws) {
  __shared__ __align__(16) unsigned int kpTu[64*68];   // [m 64][seq-pair 64 +pad4]
  __shared__ __align__(16) ushort Vts[64*136];         // [e 64][seq 128 +pad8]
  __shared__ float zred[4][64];

  const int t  = threadIdx.x;
  const int w  = t >> 6;
  const int l  = t & 63;
  const int lq = l >> 4;
  const int ln = l & 15;
  const int bh = blockIdx.x >> 2;
  const int ms = blockIdx.x & 3;        // feature slice [ms*64, ms*64+64)

  const ushort* kpb = (const ushort*)(ws + OFFB_KP) + (size_t)bh*NN*MM + ms*64;
  const ushort* vtb = (const ushort*)(ws + OFFB_VT) + (size_t)bh*DH*NN;
  ushort* spb = (ushort*)(ws + OFFB_SP) + (size_t)bh*NCH*DH*MM + ms*64;
  float*  zb  = (float*)(ws + OFFB_Z) + (size_t)bh*NCH*MM + ms*64;

  f32x4 acc[4];
  #pragma unroll
  for (int nt = 0; nt < 4; ++nt) acc[nt] = (f32x4){0.f,0.f,0.f,0.f};
  float zrun = 0.f;

  for (int tc = 0; tc < NCH; ++tc) {
    __syncthreads();   // prev MFMA/z reads done; zred(prev) stable

    // exclusive z prefix (t<64 holds zrun for m = ms*64 + t)
    if (t < 64) {
      if (tc > 0) zrun += zred[0][t] + zred[1][t] + zred[2][t] + zred[3][t];
      zb[(size_t)tc*MM + t] = zrun;
    }
    // exclusive S prefix: dump current acc (C-layout: row=e, col=m)
    {
      ushort* sp = spb + (size_t)tc*DH*MM;
      #pragma unroll
      for (int nt = 0; nt < 4; ++nt)
        #pragma unroll
        for (int reg = 0; reg < 4; ++reg)
          sp[(size_t)(w*16 + lq*4 + reg)*MM + nt*16 + ln] = f2b(acc[nt][reg]);
    }

    // stage kpT as ushort pairs: kpTu[m][jp] = kp[2jp][m] | kp[2jp+1][m]<<16
    const ushort* kslice = kpb + (size_t)tc*CHK*MM;
    #pragma unroll
    for (int it = 0; it < 2; ++it) {
      int slot = t + 256*it;           // < 512
      int jp = slot >> 3, mo = slot & 7;
      short8 a = *(const short8*)(kslice + (size_t)(2*jp)*MM + mo*8);
      short8 c = *(const short8*)(kslice + (size_t)(2*jp+1)*MM + mo*8);
      #pragma unroll
      for (int i = 0; i < 8; ++i) {
        unsigned int u = (unsigned int)(unsigned short)a[i]
                       | ((unsigned int)(unsigned short)c[i] << 16);
        kpTu[(mo*8 + i)*68 + jp] = u;
      }
    }
    // stage Vt chunk [64 e][128 seq]
    #pragma unroll
    for (int it = 0; it < 4; ++it) {
      int slot = t + 256*it;           // < 1024
      int e = slot >> 4, g = slot & 15;
      *(short8*)(Vts + e*136 + g*8) = *(const short8*)(vtb + (size_t)e*NN + tc*CHK + g*8);
    }
    __syncthreads();

    // z partials for this chunk (consumed at next loop top)
    {
      int m = t & 63, q = t >> 6;
      float s = 0.f;
      #pragma unroll
      for (int u = 0; u < 16; ++u) {
        unsigned int p = kpTu[m*68 + q*16 + u];
        s += b2f((ushort)(p & 0xFFFF)) + b2f((ushort)(p >> 16));
      }
      zred[q][m] = s;
    }

    // MFMA accumulate: D[e][m] += sum_k Vt[e][k] * kpT[m][k]
    #pragma unroll
    for (int kk = 0; kk < 4; ++kk) {
      short8 af = *(const short8*)(Vts + (w*16 + ln)*136 + kk*32 + lq*8);
      #pragma unroll
      for (int nt = 0; nt < 4; ++nt) {
        short8 bf = *(const short8*)((const ushort*)kpTu + ((size_t)(nt*16 + ln)*68 + kk*16 + lq*4)*2);
        acc[nt] = MFMA(af, bf, acc[nt]);
      }
    }
  }
}

// ---------------------------------------------------------------------------
// Fused per-chunk kernel: Sc = Qp Kp^T (MFMA, lower-tri tiles only), tril mask
// + rowsum in C-layout regs, den = qp.(z_prev+eps) + rowsum, P->LDS (A-layout),
// out = (P V + Qp S_prev) * 1/den.
// ---------------------------------------------------------------------------
__global__ __launch_bounds__(256) void fused_kernel(float* __restrict__ out,
                                                    char* __restrict__ ws) {
  __shared__ __align__(16) char lds[52224];
  __shared__ float den_i[128];
  __shared__ float dinv_s[128];

  const int t  = threadIdx.x;
  const int w  = t >> 6;
  const int l  = t & 63;
  const int lq = l >> 4;
  const int ln = l & 15;
  const int blk = blockIdx.x;
  const int bh = blk >> 4, tc = blk & 15;
  const int b = bh >> 3, h = bh & 7;
  const size_t rowbase = (size_t)bh*NN + tc*CHK;

  const ushort* qpg = (const ushort*)(ws + OFFB_QP) + rowbase*MM;
  const ushort* kpg = (const ushort*)(ws + OFFB_KP) + rowbase*MM;

  // ---- Phase A: Sc = Qp Kp^T, K=256 in 4 chunks of 64 ----
  ushort* qs = (ushort*)lds;            // [128][72]
  ushort* ks = qs + 128*72;             // [128][72]

  f32x4 acc[2][8];
  #pragma unroll
  for (int mt = 0; mt < 2; ++mt)
    #pragma unroll
    for (int nt = 0; nt < 8; ++nt) acc[mt][nt] = (f32x4){0.f,0.f,0.f,0.f};

  const int ntmax = 2*w + 2;

  for (int mc = 0; mc < 4; ++mc) {
    __syncthreads();
    #pragma unroll
    for (int ld2 = 0; ld2 < 4; ++ld2) {
      int flat = t + 256*ld2; int r = flat >> 3, g = flat & 7;
      *(short8*)(qs + r*72 + g*8) = *(const short8*)(qpg + (size_t)r*MM + mc*64 + g*8);
      *(short8*)(ks + r*72 + g*8) = *(const short8*)(kpg + (size_t)r*MM + mc*64 + g*8);
    }
    __syncthreads();
    #pragma unroll
    for (int kk = 0; kk < 2; ++kk) {
      short8 af0 = *(const short8*)(qs + (w*32 +      ln)*72 + kk*32 + lq*8);
      short8 af1 = *(const short8*)(qs + (w*32 + 16 + ln)*72 + kk*32 + lq*8);
      #pragma unroll
      for (int nt = 0; nt < 8; ++nt) {
        if (nt < ntmax) {
          short8 bf = *(const short8*)(ks + (nt*16 + ln)*72 + kk*32 + lq*8);
          acc[0][nt] = MFMA(af0, bf, acc[0][nt]);
          acc[1][nt] = MFMA(af1, bf, acc[1][nt]);
        }
      }
    }
  }

  __syncthreads();

  ushort* P   = (ushort*)lds;             // [128][136]
  ushort* Vts = (ushort*)(lds + 34816);   // [64][136]

  float rs[2][4] = {{0,0,0,0},{0,0,0,0}};
  #pragma unroll
  for (int mt = 0; mt < 2; ++mt)
    #pragma unroll
    for (int nt = 0; nt < 8; ++nt)
      #pragma unroll
      for (int reg = 0; reg < 4; ++reg) {
        int i = w*32 + mt*16 + lq*4 + reg;
        int j = nt*16 + ln;
        float v = (j <= i) ? acc[mt][nt][reg] : 0.f;
        rs[mt][reg] += v;
        P[i*136 + j] = f2b(v);
      }
  #pragma unroll
  for (int mt = 0; mt < 2; ++mt)
    #pragma unroll
    for (int reg = 0; reg < 4; ++reg) {
      float s = rs[mt][reg];
      s += __shfl_xor(s, 1); s += __shfl_xor(s, 2);
      s += __shfl_xor(s, 4); s += __shfl_xor(s, 8);
      if (ln == 0) den_i[w*32 + mt*16 + lq*4 + reg] = s;
    }

  const ushort* vtg = (const ushort*)(ws + OFFB_VT) + (size_t)bh*DH*NN + tc*CHK;
  #pragma unroll
  for (int ld2 = 0; ld2 < 4; ++ld2) {
    int flat = t + 256*ld2; int e = flat >> 4, g = flat & 15;
    *(short8*)(Vts + e*136 + g*8) = *(const short8*)(vtg + (size_t)e*NN + g*8);
  }
  __syncthreads();

  {
    const float* zp = (const float*)(ws + OFFB_Z) + (size_t)blk*MM;
    const int r = t >> 1, hf = t & 1;
    const ushort* qrow = qpg + (size_t)r*MM + hf*128;
    float s = 0.f;
    #pragma unroll
    for (int g = 0; g < 16; ++g) {
      short8 qv = *(const short8*)(qrow + g*8);
      const float* zz = zp + hf*128 + g*8;
      #pragma unroll
      for (int x = 0; x < 8; ++x)
        s += b2f((ushort)qv[x]) * (zz[x] + EPSD);
    }
    s += __shfl_xor(s, 1);
    if (hf == 0) dinv_s[r] = 1.0f / (s + den_i[r]);
  }

  f32x4 oacc[2][4];
  #pragma unroll
  for (int mt = 0; mt < 2; ++mt)
    #pragma unroll
    for (int nt = 0; nt < 4; ++nt) oacc[mt][nt] = (f32x4){0.f,0.f,0.f,0.f};

  #pragma unroll
  for (int kk = 0; kk < 4; ++kk) {
    short8 af0 = *(const short8*)(P + (w*32 +      ln)*136 + kk*32 + lq*8);
    short8 af1 = *(const short8*)(P + (w*32 + 16 + ln)*136 + kk*32 + lq*8);
    #pragma unroll
    for (int nt = 0; nt < 4; ++nt) {
      short8 bf = *(const short8*)(Vts + (nt*16 + ln)*136 + kk*32 + lq*8);
      oacc[0][nt] = MFMA(af0, bf, oacc[0][nt]);
      oacc[1][nt] = MFMA(af1, bf, oacc[1][nt]);
    }
  }
  __syncthreads();

  ushort* qs2 = (ushort*)lds;           // [128][72]
  ushort* ss  = qs2 + 128*72;           // [64][72]
  const ushort* spg = (const ushort*)(ws + OFFB_SP) + (size_t)blk*DH*MM;
  for (int mc = 0; mc < 4; ++mc) {
    if (mc) __syncthreads();
    #pragma unroll
    for (int ld2 = 0; ld2 < 4; ++ld2) {
      int flat = t + 256*ld2; int r = flat >> 3, g = flat & 7;
      *(short8*)(qs2 + r*72 + g*8) = *(const short8*)(qpg + (size_t)r*MM + mc*64 + g*8);
    }
    #pragma unroll
    for (int ld2 = 0; ld2 < 2; ++ld2) {
      int flat = t + 256*ld2; int e = flat >> 3, g = flat & 7;
      *(short8*)(ss + e*72 + g*8) = *(const short8*)(spg + (size_t)e*MM + mc*64 + g*8);
    }
    __syncthreads();
    #pragma unroll
    for (int kk = 0; kk < 2; ++kk) {
      short8 af0 = *(const short8*)(qs2 + (w*32 +      ln)*72 + kk*32 + lq*8);
      short8 af1 = *(const short8*)(qs2 + (w*32 + 16 + ln)*72 + kk*32 + lq*8);
      #pragma unroll
      for (int nt = 0; nt < 4; ++nt) {
        short8 bf = *(const short8*)(ss + (nt*16 + ln)*72 + kk*32 + lq*8);
        oacc[0][nt] = MFMA(af0, bf, oacc[0][nt]);
        oacc[1][nt] = MFMA(af1, bf, oacc[1][nt]);
      }
    }
  }

  #pragma unroll
  for (int mt = 0; mt < 2; ++mt)
    #pragma unroll
    for (int reg = 0; reg < 4; ++reg) {
      const int i = w*32 + mt*16 + lq*4 + reg;
      const float di = dinv_s[i];
      float* dst = out + ((size_t)(b*NN) + tc*CHK + i)*DD + h*DH;
      #pragma unroll
      for (int nt = 0; nt < 4; ++nt)
        dst[nt*16 + ln] = oacc[mt][nt][reg] * di;
    }
}

extern "C" void kernel_launch(void* const* d_in, const int* in_sizes, int n_in,
                              void* d_out, int out_size, void* d_ws, size_t ws_size,
                              hipStream_t stream) {
  (void)in_sizes; (void)n_in; (void)out_size; (void)ws_size;
  const float* q    = (const float*)d_in[0];
  const float* k    = (const float*)d_in[1];
  const float* v    = (const float*)d_in[2];
  const float* proj = (const float*)d_in[3];
  float* out = (float*)d_out;
  char*  ws  = (char*)d_ws;

  featm_kernel<0><<<1024, 256, 0, stream>>>(q, proj, ws);
  featm_kernel<1><<<1024, 256, 0, stream>>>(k, proj, ws);
  kmax_kernel<<<1, 256, 0, stream>>>(ws);
  featm_kernel<2><<<1024, 256, 0, stream>>>(k, proj, ws);
  vt_kernel<<<512, 256, 0, stream>>>(v, ws);
  sprefix_kernel<<<128, 256, 0, stream>>>(ws);
  fused_kernel<<<512, 256, 0, stream>>>(out, ws);
}

// Round 6
// 194.946 us; speedup vs baseline: 3.9032x; 1.0454x over previous
//
#include <hip/hip_runtime.h>
#include <math.h>

#define BB 4
#define NN 2048
#define DD 512
#define HH 8
#define DH 64
#define MM 256
#define BH 32            // B*H
#define CHK 128
#define NCH 16           // N / CHK
#define ROWS (BH*NN)     // 65536

constexpr float NRM   = 0.35355339059327373f;  // 64^-0.25
constexpr float RATIO = 0.0625f;               // 256^-0.5
constexpr float EPSK  = 1e-4f;
constexpr float EPSD  = 1e-6f;

// ---------------- workspace byte offsets ----------------
#define OFFB_QP   ((size_t)0)
#define OFFB_SP   ((size_t)33554432)
#define OFFB_KP   (OFFB_SP + (size_t)16777216)
#define OFFB_VT   (OFFB_KP + (size_t)33554432)
#define OFFB_Z    (OFFB_VT + (size_t)8388608)
#define OFFB_KMP  (OFFB_Z  + (size_t)524288)

typedef __attribute__((ext_vector_type(8))) short short8;
typedef __attribute__((ext_vector_type(4))) float f32x4;

__device__ __forceinline__ float b2f(ushort u) {
  union { float f; unsigned int i; } x; x.i = ((unsigned int)u) << 16; return x.f;
}
__device__ __forceinline__ ushort f2b(float f) {  // RNE
  unsigned int u = __float_as_uint(f);
  unsigned int r = (u + 0x7FFFu + ((u >> 16) & 1u)) >> 16;
  return (ushort)r;
}

#define MFMA(a,b,c) __builtin_amdgcn_mfma_f32_16x16x32_bf16(a, b, c, 0, 0, 0)

// ---------------------------------------------------------------------------
// Feature body. 64 rows/block, all 256 features, split-A (hi+lo) bf16 MFMA.
// MODE 0 (Q): per-row max, exp -> qp bf16. MODE 1: block max of raw dash.
// MODE 2 (KP): per-bh max (reduced inline from kmp), exp -> kp bf16.
// ---------------------------------------------------------------------------
template<int MODE>
__device__ __forceinline__ void featm_body(const float* __restrict__ inp,
                                           const float* __restrict__ proj,
                                           char* __restrict__ ws,
                                           char* lds, int blk) {
  ushort* xh = (ushort*)lds;              // [64][72]
  ushort* xl = xh + 64*72;                // [64][72]
  ushort* ps = xl + 64*72;                // [256][72]
  ushort* qt = ps;                        // [64][264] (overlaps ps)
  float* diag_s = (float*)(lds + 55296);  // [64]
  float (*wmax)[4] = (float(*)[4])(lds + 55552);   // [64][4]
  float* kred = (float*)(lds + 56576);    // [4] (MODE1) / km_s (MODE2)

  const int t  = threadIdx.x;
  const int w  = t >> 6;
  const int l  = t & 63;
  const int lq = l >> 4;
  const int ln = l & 15;

  const int rowbase = blk * 64;
  const int bh = rowbase >> 11;
  const int b  = bh >> 3, h = bh & 7;
  const int n0 = rowbase & (NN - 1);

  // ---- stage X (scaled, hi/lo split) + diag ----
  {
    const int r  = t >> 2;
    const int c0 = (t & 3) * 16;
    const float* src = inp + ((size_t)(b*NN + n0 + r))*DD + h*DH + c0;
    float vv[16];
    #pragma unroll
    for (int j = 0; j < 4; ++j) {
      float4 v = *(const float4*)(src + j*4);
      vv[4*j+0] = v.x*NRM; vv[4*j+1] = v.y*NRM;
      vv[4*j+2] = v.z*NRM; vv[4*j+3] = v.w*NRM;
    }
    float s = 0.f;
    ushort hi[16], lo[16];
    #pragma unroll
    for (int j = 0; j < 16; ++j) {
      s += vv[j]*vv[j];
      hi[j] = f2b(vv[j]);
      lo[j] = f2b(vv[j] - b2f(hi[j]));
    }
    *(short8*)(xh + r*72 + c0)     = *(short8*)&hi[0];
    *(short8*)(xh + r*72 + c0 + 8) = *(short8*)&hi[8];
    *(short8*)(xl + r*72 + c0)     = *(short8*)&lo[0];
    *(short8*)(xl + r*72 + c0 + 8) = *(short8*)&lo[8];
    s += __shfl_xor(s, 1); s += __shfl_xor(s, 2);
    if ((t & 3) == 0) diag_s[r] = 0.5f * s;
  }
  // ---- stage proj bf16 [256][72] ----
  #pragma unroll
  for (int ld = 0; ld < 4; ++ld) {
    int flat = t + 256*ld;             // < 1024
    int r = flat >> 2, c0 = (flat & 3) * 16;
    const float* src = proj + (size_t)r*DH + c0;
    ushort hv[16];
    #pragma unroll
    for (int j = 0; j < 4; ++j) {
      float4 v = *(const float4*)(src + j*4);
      hv[4*j+0] = f2b(v.x); hv[4*j+1] = f2b(v.y);
      hv[4*j+2] = f2b(v.z); hv[4*j+3] = f2b(v.w);
    }
    *(short8*)(ps + r*72 + c0)     = *(short8*)&hv[0];
    *(short8*)(ps + r*72 + c0 + 8) = *(short8*)&hv[8];
  }
  __syncthreads();

  // ---- MFMA: wave w covers features [w*64, w*64+64) ----
  f32x4 acc[4][4];
  #pragma unroll
  for (int mt = 0; mt < 4; ++mt)
    #pragma unroll
    for (int nt = 0; nt < 4; ++nt) acc[mt][nt] = (f32x4){0.f,0.f,0.f,0.f};

  #pragma unroll
  for (int kk = 0; kk < 2; ++kk) {
    short8 ah[4], al[4];
    #pragma unroll
    for (int mt = 0; mt < 4; ++mt) {
      ah[mt] = *(const short8*)(xh + (mt*16 + ln)*72 + kk*32 + lq*8);
      al[mt] = *(const short8*)(xl + (mt*16 + ln)*72 + kk*32 + lq*8);
    }
    #pragma unroll
    for (int nt = 0; nt < 4; ++nt) {
      short8 bf = *(const short8*)(ps + (w*64 + nt*16 + ln)*72 + kk*32 + lq*8);
      #pragma unroll
      for (int mt = 0; mt < 4; ++mt) {
        acc[mt][nt] = MFMA(al[mt], bf, acc[mt][nt]);
        acc[mt][nt] = MFMA(ah[mt], bf, acc[mt][nt]);
      }
    }
  }

  if (MODE == 1) {
    float mx = -1e30f;
    #pragma unroll
    for (int mt = 0; mt < 4; ++mt)
      #pragma unroll
      for (int nt = 0; nt < 4; ++nt)
        #pragma unroll
        for (int reg = 0; reg < 4; ++reg) mx = fmaxf(mx, acc[mt][nt][reg]);
    #pragma unroll
    for (int m = 1; m < 64; m <<= 1) mx = fmaxf(mx, __shfl_xor(mx, m));
    if (l == 0) kred[w] = mx;
    __syncthreads();
    if (t == 0)
      ((float*)(ws + OFFB_KMP))[blk] =
        fmaxf(fmaxf(kred[0], kred[1]), fmaxf(kred[2], kred[3]));
    return;
  }

  if (MODE == 0) {
    #pragma unroll
    for (int mt = 0; mt < 4; ++mt)
      #pragma unroll
      for (int reg = 0; reg < 4; ++reg) {
        float m = acc[mt][0][reg];
        #pragma unroll
        for (int nt = 1; nt < 4; ++nt) m = fmaxf(m, acc[mt][nt][reg]);
        m = fmaxf(m, __shfl_xor(m, 1));
        m = fmaxf(m, __shfl_xor(m, 2));
        m = fmaxf(m, __shfl_xor(m, 4));
        m = fmaxf(m, __shfl_xor(m, 8));
        if (ln == 0) wmax[mt*16 + lq*4 + reg][w] = m;
      }
  }
  if (MODE == 2) {
    // inline per-bh kmax reduce from the 32 per-block partials
    if (t < 32) {
      float m = ((const float*)(ws + OFFB_KMP))[bh*32 + t];
      #pragma unroll
      for (int d = 1; d < 32; d <<= 1) m = fmaxf(m, __shfl_xor(m, d));
      if (t == 0) kred[0] = m;
    }
  }
  __syncthreads();   // wmax/km ready; ps reads done -> qt region safe

  float km = 0.f;
  if (MODE == 2) km = kred[0];

  #pragma unroll
  for (int mt = 0; mt < 4; ++mt)
    #pragma unroll
    for (int reg = 0; reg < 4; ++reg) {
      const int row = mt*16 + lq*4 + reg;
      float rm;
      if (MODE == 0) {
        float4 wm4 = *(const float4*)&wmax[row][0];
        rm = fmaxf(fmaxf(wm4.x, wm4.y), fmaxf(wm4.z, wm4.w));
      } else {
        rm = km;
      }
      const float dg = diag_s[row];
      #pragma unroll
      for (int nt = 0; nt < 4; ++nt)
        qt[row*264 + w*64 + nt*16 + ln] =
          f2b(RATIO*(expf(acc[mt][nt][reg] - dg - rm) + EPSK));
    }
  __syncthreads();

  ushort* dstbase = (ushort*)(ws + (MODE == 0 ? OFFB_QP : OFFB_KP)) + (size_t)rowbase*MM;
  #pragma unroll
  for (int ld = 0; ld < 8; ++ld) {
    int flat = t + 256*ld;             // < 2048
    int row = flat >> 5, g = flat & 31;
    *(short8*)(dstbase + (size_t)row*MM + g*8) = *(const short8*)(qt + row*264 + g*8);
  }
}

// Vt[bh][e][n] = bf16(V[b][n][h*64+e])
__device__ __forceinline__ void vt_body(const float* __restrict__ value,
                                        char* __restrict__ ws,
                                        char* lds, int blk) {
  float (*vsh)[68] = (float(*)[68])lds;   // [128][68]
  const int t = threadIdx.x;
  const int bh = blk >> 4, nc = blk & 15;
  const int b = bh >> 3, h = bh & 7;
  const int n0 = nc * CHK;
  #pragma unroll
  for (int l = 0; l < 8; ++l) {
    int flat = t + 256*l;
    int r = flat >> 4, g = flat & 15;
    *(float4*)&vsh[r][g*4] = *(const float4*)(value + ((size_t)(b*NN + n0 + r))*DD + h*DH + g*4);
  }
  __syncthreads();
  const int e = t & 63, qd = t >> 6;
  ushort* vt = (ushort*)(ws + OFFB_VT) + ((size_t)bh*DH + e)*NN + n0 + qd*32;
  #pragma unroll
  for (int p = 0; p < 16; ++p) {
    unsigned int lo = f2b(vsh[qd*32 + 2*p][e]);
    unsigned int hi = f2b(vsh[qd*32 + 2*p + 1][e]);
    ((unsigned int*)vt)[p] = lo | (hi << 16);
  }
}

// mega: blocks [0,1024) featQ; [1024,2048) featK-max; [2048,2560) V-transpose
__global__ __launch_bounds__(256) void mega_kernel(const float* __restrict__ q,
                                                   const float* __restrict__ k,
                                                   const float* __restrict__ v,
                                                   const float* __restrict__ proj,
                                                   char* __restrict__ ws) {
  __shared__ __align__(16) char lds[56832];
  const int blk = blockIdx.x;
  if (blk < 1024)       featm_body<0>(q, proj, ws, lds, blk);
  else if (blk < 2048)  featm_body<1>(k, proj, ws, lds, blk - 1024);
  else                  vt_body(v, ws, lds, blk - 2048);
}

__global__ __launch_bounds__(256) void featm2_kernel(const float* __restrict__ k,
                                                     const float* __restrict__ proj,
                                                     char* __restrict__ ws) {
  __shared__ __align__(16) char lds[56832];
  featm_body<2>(k, proj, ws, lds, blockIdx.x);
}

// ---------------------------------------------------------------------------
// MFMA chunk-scan: per (bh, 32-feature slice) block (256 blocks), sequential
// over 16 chunks: dump exclusive-prefix acc -> SP/z, then MFMA-accumulate
// G_tc = Vt_chunk x kpT_chunk into the C registers.
// ---------------------------------------------------------------------------
__global__ __launch_bounds__(256) void sprefix_kernel(char* __restrict__ ws) {
  __shared__ __align__(16) unsigned int kpTu[32*68];   // [m 32][seq-pair 64 +pad]
  __shared__ __align__(16) ushort Vts[64*136];         // [e 64][seq 128 +pad]
  __shared__ float zred[8][32];

  const int t  = threadIdx.x;
  const int w  = t >> 6;
  const int l  = t & 63;
  const int lq = l >> 4;
  const int ln = l & 15;
  const int bh = blockIdx.x >> 3;
  const int ms = blockIdx.x & 7;        // feature slice [ms*32, ms*32+32)

  const ushort* kpb = (const ushort*)(ws + OFFB_KP) + (size_t)bh*NN*MM + ms*32;
  const ushort* vtb = (const ushort*)(ws + OFFB_VT) + (size_t)bh*DH*NN;
  ushort* spb = (ushort*)(ws + OFFB_SP) + (size_t)bh*NCH*DH*MM + ms*32;
  float*  zb  = (float*)(ws + OFFB_Z) + (size_t)bh*NCH*MM + ms*32;

  f32x4 acc[2];
  acc[0] = (f32x4){0.f,0.f,0.f,0.f};
  acc[1] = (f32x4){0.f,0.f,0.f,0.f};
  float zrun = 0.f;

  for (int tc = 0; tc < NCH; ++tc) {
    __syncthreads();   // prev MFMA/z reads done; zred(prev) stable

    if (t < 32) {
      if (tc > 0) {
        float s = 0.f;
        #pragma unroll
        for (int q = 0; q < 8; ++q) s += zred[q][t];
        zrun += s;
      }
      zb[(size_t)tc*MM + t] = zrun;
    }
    // dump exclusive S prefix (C-layout: row=e, col=m)
    {
      ushort* sp = spb + (size_t)tc*DH*MM;
      #pragma unroll
      for (int nt = 0; nt < 2; ++nt)
        #pragma unroll
        for (int reg = 0; reg < 4; ++reg)
          sp[(size_t)(w*16 + lq*4 + reg)*MM + nt*16 + ln] = f2b(acc[nt][reg]);
    }

    // stage kpT as ushort pairs: kpTu[m][jp] = kp[2jp][m] | kp[2jp+1][m]<<16
    const ushort* kslice = kpb + (size_t)tc*CHK*MM;
    {
      int jp = t >> 2, mo = t & 3;      // 64 x 4 = 256 slots
      short8 a = *(const short8*)(kslice + (size_t)(2*jp)*MM + mo*8);
      short8 c = *(const short8*)(kslice + (size_t)(2*jp+1)*MM + mo*8);
      #pragma unroll
      for (int i = 0; i < 8; ++i) {
        unsigned int u = (unsigned int)(unsigned short)a[i]
                       | ((unsigned int)(unsigned short)c[i] << 16);
        kpTu[(mo*8 + i)*68 + jp] = u;
      }
    }
    // stage Vt chunk [64 e][128 seq]
    #pragma unroll
    for (int it = 0; it < 4; ++it) {
      int slot = t + 256*it;           // < 1024
      int e = slot >> 4, g = slot & 15;
      *(short8*)(Vts + e*136 + g*8) = *(const short8*)(vtb + (size_t)e*NN + tc*CHK + g*8);
    }
    __syncthreads();

    // z partials (consumed at next loop top): 256 threads, 8 jp-octants x 32 m
    {
      int m = t & 31, q = t >> 5;
      float s = 0.f;
      #pragma unroll
      for (int u = 0; u < 8; ++u) {
        unsigned int p = kpTu[m*68 + q*8 + u];
        s += b2f((ushort)(p & 0xFFFF)) + b2f((ushort)(p >> 16));
      }
      zred[q][m] = s;
    }

    // MFMA: D[e][m] += sum_k Vt[e][k] * kpT[m][k]; wave w owns e-tile w
    #pragma unroll
    for (int kk = 0; kk < 4; ++kk) {
      short8 af = *(const short8*)(Vts + (w*16 + ln)*136 + kk*32 + lq*8);
      #pragma unroll
      for (int nt = 0; nt < 2; ++nt) {
        short8 bf = *(const short8*)((const ushort*)kpTu + (size_t)(nt*16 + ln)*136 + kk*32 + lq*8);
        acc[nt] = MFMA(af, bf, acc[nt]);
      }
    }
  }
}

// ---------------------------------------------------------------------------
// Fused per-chunk kernel, balanced waves: wave w owns row-tiles {w, 7-w}
// (9 lower-tri tile-columns per wave instead of up-to-16).
// ---------------------------------------------------------------------------
__global__ __launch_bounds__(256) void fused_kernel(float* __restrict__ out,
                                                    char* __restrict__ ws) {
  __shared__ __align__(16) char lds[52224];
  __shared__ float den_i[128];
  __shared__ float dinv_s[128];

  const int t  = threadIdx.x;
  const int w  = t >> 6;
  const int l  = t & 63;
  const int lq = l >> 4;
  const int ln = l & 15;
  const int rt0 = w;          // row-tile A
  const int rt1 = 7 - w;      // row-tile B  (rt0 < rt1 always)
  const int blk = blockIdx.x;
  const int bh = blk >> 4, tc = blk & 15;
  const int b = bh >> 3, h = bh & 7;
  const size_t rowbase = (size_t)bh*NN + tc*CHK;

  const ushort* qpg = (const ushort*)(ws + OFFB_QP) + rowbase*MM;
  const ushort* kpg = (const ushort*)(ws + OFFB_KP) + rowbase*MM;

  // ---- Phase A: Sc = Qp Kp^T, K=256 in 4 chunks of 64 ----
  ushort* qs = (ushort*)lds;            // [128][72]
  ushort* ks = qs + 128*72;             // [128][72]

  f32x4 acc[2][8];
  #pragma unroll
  for (int mt = 0; mt < 2; ++mt)
    #pragma unroll
    for (int nt = 0; nt < 8; ++nt) acc[mt][nt] = (f32x4){0.f,0.f,0.f,0.f};

  for (int mc = 0; mc < 4; ++mc) {
    __syncthreads();
    #pragma unroll
    for (int ld2 = 0; ld2 < 4; ++ld2) {
      int flat = t + 256*ld2; int r = flat >> 3, g = flat & 7;
      *(short8*)(qs + r*72 + g*8) = *(const short8*)(qpg + (size_t)r*MM + mc*64 + g*8);
      *(short8*)(ks + r*72 + g*8) = *(const short8*)(kpg + (size_t)r*MM + mc*64 + g*8);
    }
    __syncthreads();
    #pragma unroll
    for (int kk = 0; kk < 2; ++kk) {
      short8 af0 = *(const short8*)(qs + (rt0*16 + ln)*72 + kk*32 + lq*8);
      short8 af1 = *(const short8*)(qs + (rt1*16 + ln)*72 + kk*32 + lq*8);
      #pragma unroll
      for (int nt = 0; nt < 8; ++nt) {
        if (nt <= rt1) {
          short8 bf = *(const short8*)(ks + (nt*16 + ln)*72 + kk*32 + lq*8);
          if (nt <= rt0) acc[0][nt] = MFMA(af0, bf, acc[0][nt]);
          acc[1][nt] = MFMA(af1, bf, acc[1][nt]);
        }
      }
    }
  }

  __syncthreads();

  ushort* P   = (ushort*)lds;             // [128][136]
  ushort* Vts = (ushort*)(lds + 34816);   // [64][136]

  float rs[2][4] = {{0,0,0,0},{0,0,0,0}};
  #pragma unroll
  for (int mt = 0; mt < 2; ++mt) {
    const int ibase = (mt ? rt1 : rt0) * 16;
    #pragma unroll
    for (int nt = 0; nt < 8; ++nt)
      #pragma unroll
      for (int reg = 0; reg < 4; ++reg) {
        int i = ibase + lq*4 + reg;
        int j = nt*16 + ln;
        float v = (j <= i) ? acc[mt][nt][reg] : 0.f;
        rs[mt][reg] += v;
        P[i*136 + j] = f2b(v);
      }
  }
  #pragma unroll
  for (int mt = 0; mt < 2; ++mt) {
    const int ibase = (mt ? rt1 : rt0) * 16;
    #pragma unroll
    for (int reg = 0; reg < 4; ++reg) {
      float s = rs[mt][reg];
      s += __shfl_xor(s, 1); s += __shfl_xor(s, 2);
      s += __shfl_xor(s, 4); s += __shfl_xor(s, 8);
      if (ln == 0) den_i[ibase + lq*4 + reg] = s;
    }
  }

  const ushort* vtg = (const ushort*)(ws + OFFB_VT) + (size_t)bh*DH*NN + tc*CHK;
  #pragma unroll
  for (int ld2 = 0; ld2 < 4; ++ld2) {
    int flat = t + 256*ld2; int e = flat >> 4, g = flat & 15;
    *(short8*)(Vts + e*136 + g*8) = *(const short8*)(vtg + (size_t)e*NN + g*8);
  }
  __syncthreads();

  {
    const float* zp = (const float*)(ws + OFFB_Z) + (size_t)blk*MM;
    const int r = t >> 1, hf = t & 1;
    const ushort* qrow = qpg + (size_t)r*MM + hf*128;
    float s = 0.f;
    #pragma unroll
    for (int g = 0; g < 16; ++g) {
      short8 qv = *(const short8*)(qrow + g*8);
      const float* zz = zp + hf*128 + g*8;
      #pragma unroll
      for (int x = 0; x < 8; ++x)
        s += b2f((ushort)qv[x]) * (zz[x] + EPSD);
    }
    s += __shfl_xor(s, 1);
    if (hf == 0) dinv_s[r] = 1.0f / (s + den_i[r]);
  }

  f32x4 oacc[2][4];
  #pragma unroll
  for (int mt = 0; mt < 2; ++mt)
    #pragma unroll
    for (int nt = 0; nt < 4; ++nt) oacc[mt][nt] = (f32x4){0.f,0.f,0.f,0.f};

  #pragma unroll
  for (int kk = 0; kk < 4; ++kk) {
    short8 af0 = *(const short8*)(P + (rt0*16 + ln)*136 + kk*32 + lq*8);
    short8 af1 = *(const short8*)(P + (rt1*16 + ln)*136 + kk*32 + lq*8);
    #pragma unroll
    for (int nt = 0; nt < 4; ++nt) {
      short8 bf = *(const short8*)(Vts + (nt*16 + ln)*136 + kk*32 + lq*8);
      oacc[0][nt] = MFMA(af0, bf, oacc[0][nt]);
      oacc[1][nt] = MFMA(af1, bf, oacc[1][nt]);
    }
  }
  __syncthreads();

  ushort* qs2 = (ushort*)lds;           // [128][72]
  ushort* ss  = qs2 + 128*72;           // [64][72]
  const ushort* spg = (const ushort*)(ws + OFFB_SP) + (size_t)blk*DH*MM;
  for (int mc = 0; mc < 4; ++mc) {
    if (mc) __syncthreads();
    #pragma unroll
    for (int ld2 = 0; ld2 < 4; ++ld2) {
      int flat = t + 256*ld2; int r = flat >> 3, g = flat & 7;
      *(short8*)(qs2 + r*72 + g*8) = *(const short8*)(qpg + (size_t)r*MM + mc*64 + g*8);
    }
    #pragma unroll
    for (int ld2 = 0; ld2 < 2; ++ld2) {
      int flat = t + 256*ld2; int e = flat >> 3, g = flat & 7;
      *(short8*)(ss + e*72 + g*8) = *(const short8*)(spg + (size_t)e*MM + mc*64 + g*8);
    }
    __syncthreads();
    #pragma unroll
    for (int kk = 0; kk < 2; ++kk) {
      short8 af0 = *(const short8*)(qs2 + (rt0*16 + ln)*72 + kk*32 + lq*8);
      short8 af1 = *(const short8*)(qs2 + (rt1*16 + ln)*72 + kk*32 + lq*8);
      #pragma unroll
      for (int nt = 0; nt < 4; ++nt) {
        short8 bf = *(const short8*)(ss + (nt*16 + ln)*72 + kk*32 + lq*8);
        oacc[0][nt] = MFMA(af0, bf, oacc[0][nt]);
        oacc[1][nt] = MFMA(af1, bf, oacc[1][nt]);
      }
    }
  }

  #pragma unroll
  for (int mt = 0; mt < 2; ++mt) {
    const int ibase = (mt ? rt1 : rt0) * 16;
    #pragma unroll
    for (int reg = 0; reg < 4; ++reg) {
      const int i = ibase + lq*4 + reg;
      const float di = dinv_s[i];
      float* dst = out + ((size_t)(b*NN) + tc*CHK + i)*DD + h*DH;
      #pragma unroll
      for (int nt = 0; nt < 4; ++nt)
        dst[nt*16 + ln] = oacc[mt][nt][reg] * di;
    }
  }
}

extern "C" void kernel_launch(void* const* d_in, const int* in_sizes, int n_in,
                              void* d_out, int out_size, void* d_ws, size_t ws_size,
                              hipStream_t stream) {
  (void)in_sizes; (void)n_in; (void)out_size; (void)ws_size;
  const float* q    = (const float*)d_in[0];
  const float* k    = (const float*)d_in[1];
  const float* v    = (const float*)d_in[2];
  const float* proj = (const float*)d_in[3];
  float* out = (float*)d_out;
  char*  ws  = (char*)d_ws;

  mega_kernel<<<2560, 256, 0, stream>>>(q, k, v, proj, ws);
  featm2_kernel<<<1024, 256, 0, stream>>>(k, proj, ws);
  sprefix_kernel<<<256, 256, 0, stream>>>(ws);
  fused_kernel<<<512, 256, 0, stream>>>(out, ws);
}

// Round 7
// 191.025 us; speedup vs baseline: 3.9833x; 1.0205x over previous
//
#include <hip/hip_runtime.h>
#include <math.h>

#define BB 4
#define NN 2048
#define DD 512
#define HH 8
#define DH 64
#define MM 256
#define BH 32            // B*H
#define CHK 128
#define NCH 16           // N / CHK
#define ROWS (BH*NN)     // 65536

constexpr float NRM   = 0.35355339059327373f;  // 64^-0.25
constexpr float RATIO = 0.0625f;               // 256^-0.5
constexpr float EPSK  = 1e-4f;
constexpr float EPSD  = 1e-6f;

// ---------------- workspace byte offsets ----------------
#define OFFB_QP   ((size_t)0)
#define OFFB_SP   ((size_t)33554432)
#define OFFB_KP   (OFFB_SP + (size_t)16777216)
#define OFFB_VT   (OFFB_KP + (size_t)33554432)
#define OFFB_Z    (OFFB_VT + (size_t)8388608)
#define OFFB_KMP  (OFFB_Z  + (size_t)524288)
#define OFFB_PJB  (OFFB_KMP + (size_t)4096)    // proj bf16 [256][64]

typedef __attribute__((ext_vector_type(8))) short short8;
typedef __attribute__((ext_vector_type(4))) float f32x4;

__device__ __forceinline__ float b2f(ushort u) {
  union { float f; unsigned int i; } x; x.i = ((unsigned int)u) << 16; return x.f;
}
__device__ __forceinline__ ushort f2b(float f) {  // RNE
  unsigned int u = __float_as_uint(f);
  unsigned int r = (u + 0x7FFFu + ((u >> 16) & 1u)) >> 16;
  return (ushort)r;
}

#define MFMA(a,b,c) __builtin_amdgcn_mfma_f32_16x16x32_bf16(a, b, c, 0, 0, 0)

// proj fp32 [256][64] -> bf16 (done once; feat blocks then copy, not convert)
__global__ __launch_bounds__(256) void prep_kernel(const float* __restrict__ proj,
                                                   char* __restrict__ ws) {
  const int i = blockIdx.x*256 + threadIdx.x;     // 4096 threads x 4 elems
  float4 v = *(const float4*)(proj + (size_t)i*4);
  ushort4 o;
  o.x = f2b(v.x); o.y = f2b(v.y); o.z = f2b(v.z); o.w = f2b(v.w);
  *(ushort4*)((ushort*)(ws + OFFB_PJB) + (size_t)i*4) = o;
}

// ---------------------------------------------------------------------------
// Feature body. 64 rows/block, 256 features in two 128-halves (small LDS ->
// 4 blocks/CU). Split-A (hi+lo) bf16 MFMA, fp32 acc.
// MODE 0 (Q): per-row max, exp -> qp bf16. MODE 1: block max of raw dash.
// MODE 2 (KP): per-bh max (reduced inline from kmp), exp -> kp bf16.
// LDS map: xh[64][72] @0 (9216), xl @9216 (9216), ps[128][72] @18432 (18432);
// epilogue qt[64][264] @0 (33792); diag @36864, wmax @37120, kred @38144.
// ---------------------------------------------------------------------------
template<int MODE>
__device__ __forceinline__ void featm_body(const float* __restrict__ inp,
                                           const ushort* __restrict__ projb,
                                           char* __restrict__ ws,
                                           char* lds, int blk) {
  ushort* xh = (ushort*)lds;
  ushort* xl = xh + 64*72;
  ushort* ps = xl + 64*72;                 // [128][72]
  ushort* qt = (ushort*)lds;               // [64][264] (epilogue, after barrier)
  float* diag_s = (float*)(lds + 36864);
  float (*wmax)[4] = (float(*)[4])(lds + 37120);
  float* kred = (float*)(lds + 38144);

  const int t  = threadIdx.x;
  const int w  = t >> 6;
  const int l  = t & 63;
  const int lq = l >> 4;
  const int ln = l & 15;

  const int rowbase = blk * 64;
  const int bh = rowbase >> 11;
  const int b  = bh >> 3, h = bh & 7;
  const int n0 = rowbase & (NN - 1);

  // ---- stage X (scaled, hi/lo split) + diag ----
  {
    const int r  = t >> 2;
    const int c0 = (t & 3) * 16;
    const float* src = inp + ((size_t)(b*NN + n0 + r))*DD + h*DH + c0;
    float vv[16];
    #pragma unroll
    for (int j = 0; j < 4; ++j) {
      float4 v = *(const float4*)(src + j*4);
      vv[4*j+0] = v.x*NRM; vv[4*j+1] = v.y*NRM;
      vv[4*j+2] = v.z*NRM; vv[4*j+3] = v.w*NRM;
    }
    float s = 0.f;
    ushort hi[16], lo[16];
    #pragma unroll
    for (int j = 0; j < 16; ++j) {
      s += vv[j]*vv[j];
      hi[j] = f2b(vv[j]);
      lo[j] = f2b(vv[j] - b2f(hi[j]));
    }
    *(short8*)(xh + r*72 + c0)     = *(short8*)&hi[0];
    *(short8*)(xh + r*72 + c0 + 8) = *(short8*)&hi[8];
    *(short8*)(xl + r*72 + c0)     = *(short8*)&lo[0];
    *(short8*)(xl + r*72 + c0 + 8) = *(short8*)&lo[8];
    s += __shfl_xor(s, 1); s += __shfl_xor(s, 2);
    if ((t & 3) == 0) diag_s[r] = 0.5f * s;
  }

  f32x4 acc[4][4];
  #pragma unroll
  for (int mt = 0; mt < 4; ++mt)
    #pragma unroll
    for (int c = 0; c < 4; ++c) acc[mt][c] = (f32x4){0.f,0.f,0.f,0.f};

  // ---- two proj halves: wave w covers features p*128 + w*32 + {0..31} ----
  #pragma unroll
  for (int p = 0; p < 2; ++p) {
    if (p) __syncthreads();               // waves done reading ps half 0
    #pragma unroll
    for (int ld = 0; ld < 4; ++ld) {
      int flat = t + 256*ld;              // < 1024 : 128 rows x 8 granules
      int r = flat >> 3, g = flat & 7;
      *(short8*)(ps + r*72 + g*8) = *(const short8*)(projb + (size_t)(p*128 + r)*DH + g*8);
    }
    __syncthreads();
    #pragma unroll
    for (int kk = 0; kk < 2; ++kk) {
      short8 ah[4], al[4];
      #pragma unroll
      for (int mt = 0; mt < 4; ++mt) {
        ah[mt] = *(const short8*)(xh + (mt*16 + ln)*72 + kk*32 + lq*8);
        al[mt] = *(const short8*)(xl + (mt*16 + ln)*72 + kk*32 + lq*8);
      }
      #pragma unroll
      for (int ntl = 0; ntl < 2; ++ntl) {
        short8 bf = *(const short8*)(ps + (w*32 + ntl*16 + ln)*72 + kk*32 + lq*8);
        #pragma unroll
        for (int mt = 0; mt < 4; ++mt) {
          acc[mt][2*p+ntl] = MFMA(al[mt], bf, acc[mt][2*p+ntl]);
          acc[mt][2*p+ntl] = MFMA(ah[mt], bf, acc[mt][2*p+ntl]);
        }
      }
    }
  }

  if (MODE == 1) {
    float mx = -1e30f;
    #pragma unroll
    for (int mt = 0; mt < 4; ++mt)
      #pragma unroll
      for (int c = 0; c < 4; ++c)
        #pragma unroll
        for (int reg = 0; reg < 4; ++reg) mx = fmaxf(mx, acc[mt][c][reg]);
    #pragma unroll
    for (int m = 1; m < 64; m <<= 1) mx = fmaxf(mx, __shfl_xor(mx, m));
    if (l == 0) kred[w] = mx;
    __syncthreads();
    if (t == 0)
      ((float*)(ws + OFFB_KMP))[blk] =
        fmaxf(fmaxf(kred[0], kred[1]), fmaxf(kred[2], kred[3]));
    return;
  }

  if (MODE == 0) {
    #pragma unroll
    for (int mt = 0; mt < 4; ++mt)
      #pragma unroll
      for (int reg = 0; reg < 4; ++reg) {
        float m = acc[mt][0][reg];
        #pragma unroll
        for (int c = 1; c < 4; ++c) m = fmaxf(m, acc[mt][c][reg]);
        m = fmaxf(m, __shfl_xor(m, 1));
        m = fmaxf(m, __shfl_xor(m, 2));
        m = fmaxf(m, __shfl_xor(m, 4));
        m = fmaxf(m, __shfl_xor(m, 8));
        if (ln == 0) wmax[mt*16 + lq*4 + reg][w] = m;
      }
  }
  if (MODE == 2) {
    if (t < 32) {
      float m = ((const float*)(ws + OFFB_KMP))[bh*32 + t];
      #pragma unroll
      for (int d = 1; d < 32; d <<= 1) m = fmaxf(m, __shfl_xor(m, d));
      if (t == 0) kred[0] = m;
    }
  }
  __syncthreads();   // wmax/km ready; all ps/xh/xl reads done -> qt safe

  float km = 0.f;
  if (MODE == 2) km = kred[0];

  #pragma unroll
  for (int mt = 0; mt < 4; ++mt)
    #pragma unroll
    for (int reg = 0; reg < 4; ++reg) {
      const int row = mt*16 + lq*4 + reg;
      float rm;
      if (MODE == 0) {
        float4 wm4 = *(const float4*)&wmax[row][0];
        rm = fmaxf(fmaxf(wm4.x, wm4.y), fmaxf(wm4.z, wm4.w));
      } else {
        rm = km;
      }
      const float dg = diag_s[row];
      #pragma unroll
      for (int c = 0; c < 4; ++c) {
        const int f = (c >> 1)*128 + w*32 + (c & 1)*16 + ln;
        qt[row*264 + f] = f2b(RATIO*(__expf(acc[mt][c][reg] - dg - rm) + EPSK));
      }
    }
  __syncthreads();

  ushort* dstbase = (ushort*)(ws + (MODE == 0 ? OFFB_QP : OFFB_KP)) + (size_t)rowbase*MM;
  #pragma unroll
  for (int ld = 0; ld < 8; ++ld) {
    int flat = t + 256*ld;             // < 2048
    int row = flat >> 5, g = flat & 31;
    *(short8*)(dstbase + (size_t)row*MM + g*8) = *(const short8*)(qt + row*264 + g*8);
  }
}

// Vt[bh][e][n] = bf16(V[b][n][h*64+e])
__device__ __forceinline__ void vt_body(const float* __restrict__ value,
                                        char* __restrict__ ws,
                                        char* lds, int blk) {
  float (*vsh)[68] = (float(*)[68])lds;   // [128][68] = 34816 B
  const int t = threadIdx.x;
  const int bh = blk >> 4, nc = blk & 15;
  const int b = bh >> 3, h = bh & 7;
  const int n0 = nc * CHK;
  #pragma unroll
  for (int l = 0; l < 8; ++l) {
    int flat = t + 256*l;
    int r = flat >> 4, g = flat & 15;
    *(float4*)&vsh[r][g*4] = *(const float4*)(value + ((size_t)(b*NN + n0 + r))*DD + h*DH + g*4);
  }
  __syncthreads();
  const int e = t & 63, qd = t >> 6;
  ushort* vt = (ushort*)(ws + OFFB_VT) + ((size_t)bh*DH + e)*NN + n0 + qd*32;
  #pragma unroll
  for (int p = 0; p < 16; ++p) {
    unsigned int lo = f2b(vsh[qd*32 + 2*p][e]);
    unsigned int hi = f2b(vsh[qd*32 + 2*p + 1][e]);
    ((unsigned int*)vt)[p] = lo | (hi << 16);
  }
}

// mega: blocks [0,1024) featQ; [1024,2048) featK-max; [2048,2560) V-transpose
__global__ __launch_bounds__(256) void mega_kernel(const float* __restrict__ q,
                                                   const float* __restrict__ k,
                                                   const float* __restrict__ v,
                                                   char* __restrict__ ws) {
  __shared__ __align__(16) char lds[38160];
  const ushort* projb = (const ushort*)(ws + OFFB_PJB);
  const int blk = blockIdx.x;
  if (blk < 1024)       featm_body<0>(q, projb, ws, lds, blk);
  else if (blk < 2048)  featm_body<1>(k, projb, ws, lds, blk - 1024);
  else                  vt_body(v, ws, lds, blk - 2048);
}

__global__ __launch_bounds__(256) void featm2_kernel(const float* __restrict__ k,
                                                     char* __restrict__ ws) {
  __shared__ __align__(16) char lds[38160];
  featm_body<2>(k, (const ushort*)(ws + OFFB_PJB), ws, lds, blockIdx.x);
}

// ---------------------------------------------------------------------------
// MFMA chunk-scan, 512 blocks (bh x 16-feature slice): per chunk, dump the
// exclusive-prefix accumulator -> SP/z, then MFMA-accumulate G_tc into C regs.
// 2 blocks/CU so barrier stalls overlap across blocks.
// ---------------------------------------------------------------------------
__global__ __launch_bounds__(256) void sprefix_kernel(char* __restrict__ ws) {
  __shared__ __align__(16) unsigned int kpTu[16*68];   // [m 16][seq-pair 64 +pad]
  __shared__ __align__(16) ushort Vts[64*136];         // [e 64][seq 128 +pad]
  __shared__ float zred[16][16];

  const int t  = threadIdx.x;
  const int w  = t >> 6;
  const int l  = t & 63;
  const int lq = l >> 4;
  const int ln = l & 15;
  const int bh = blockIdx.x >> 4;
  const int ms = blockIdx.x & 15;       // feature slice [ms*16, ms*16+16)

  const ushort* kpb = (const ushort*)(ws + OFFB_KP) + (size_t)bh*NN*MM + ms*16;
  const ushort* vtb = (const ushort*)(ws + OFFB_VT) + (size_t)bh*DH*NN;
  ushort* spb = (ushort*)(ws + OFFB_SP) + (size_t)bh*NCH*DH*MM + ms*16;
  float*  zb  = (float*)(ws + OFFB_Z) + (size_t)bh*NCH*MM + ms*16;

  f32x4 acc = (f32x4){0.f,0.f,0.f,0.f};
  float zrun = 0.f;

  for (int tc = 0; tc < NCH; ++tc) {
    __syncthreads();   // prev MFMA/z reads done; zred(prev) stable

    if (t < 16) {
      if (tc > 0) {
        float s = 0.f;
        #pragma unroll
        for (int q = 0; q < 16; ++q) s += zred[q][t];
        zrun += s;
      }
      zb[(size_t)tc*MM + t] = zrun;
    }
    // dump exclusive S prefix (C-layout: row=e, col=m)
    {
      ushort* sp = spb + (size_t)tc*DH*MM;
      #pragma unroll
      for (int reg = 0; reg < 4; ++reg)
        sp[(size_t)(w*16 + lq*4 + reg)*MM + ln] = f2b(acc[reg]);
    }

    // stage kpT as ushort pairs: kpTu[m][jp] = kp[2jp][m] | kp[2jp+1][m]<<16
    const ushort* kslice = kpb + (size_t)tc*CHK*MM;
    if (t < 128) {
      int jp = t >> 1, mo = t & 1;      // 64 pairs x 2 granules-of-8
      short8 a = *(const short8*)(kslice + (size_t)(2*jp)*MM + mo*8);
      short8 c = *(const short8*)(kslice + (size_t)(2*jp+1)*MM + mo*8);
      #pragma unroll
      for (int i = 0; i < 8; ++i) {
        unsigned int u = (unsigned int)(unsigned short)a[i]
                       | ((unsigned int)(unsigned short)c[i] << 16);
        kpTu[(mo*8 + i)*68 + jp] = u;
      }
    }
    // stage Vt chunk [64 e][128 seq]
    #pragma unroll
    for (int it = 0; it < 4; ++it) {
      int slot = t + 256*it;           // < 1024
      int e = slot >> 4, g = slot & 15;
      *(short8*)(Vts + e*136 + g*8) = *(const short8*)(vtb + (size_t)e*NN + tc*CHK + g*8);
    }
    __syncthreads();

    // z partials (consumed at next loop top): 16 m x 16 quad-groups of pairs
    {
      int m = t & 15, q = t >> 4;
      float s = 0.f;
      #pragma unroll
      for (int u = 0; u < 4; ++u) {
        unsigned int p = kpTu[m*68 + q*4 + u];
        s += b2f((ushort)(p & 0xFFFF)) + b2f((ushort)(p >> 16));
      }
      zred[q][m] = s;
    }

    // MFMA: D[e][m] += sum_k Vt[e][k] * kpT[m][k]; wave w owns e-tile w
    #pragma unroll
    for (int kk = 0; kk < 4; ++kk) {
      short8 af = *(const short8*)(Vts + (w*16 + ln)*136 + kk*32 + lq*8);
      short8 bf = *(const short8*)((const ushort*)kpTu + (size_t)ln*136 + kk*32 + lq*8);
      acc = MFMA(af, bf, acc);
    }
  }
}

// ---------------------------------------------------------------------------
// Fused per-chunk kernel, balanced waves: wave w owns row-tiles {w, 7-w}.
// ---------------------------------------------------------------------------
__global__ __launch_bounds__(256) void fused_kernel(float* __restrict__ out,
                                                    char* __restrict__ ws) {
  __shared__ __align__(16) char lds[52224];
  __shared__ float den_i[128];
  __shared__ float dinv_s[128];

  const int t  = threadIdx.x;
  const int w  = t >> 6;
  const int l  = t & 63;
  const int lq = l >> 4;
  const int ln = l & 15;
  const int rt0 = w;          // row-tile A
  const int rt1 = 7 - w;      // row-tile B  (rt0 < rt1)
  const int blk = blockIdx.x;
  const int bh = blk >> 4, tc = blk & 15;
  const int b = bh >> 3, h = bh & 7;
  const size_t rowbase = (size_t)bh*NN + tc*CHK;

  const ushort* qpg = (const ushort*)(ws + OFFB_QP) + rowbase*MM;
  const ushort* kpg = (const ushort*)(ws + OFFB_KP) + rowbase*MM;

  // ---- Phase A: Sc = Qp Kp^T, K=256 in 4 chunks of 64 ----
  ushort* qs = (ushort*)lds;            // [128][72]
  ushort* ks = qs + 128*72;             // [128][72]

  f32x4 acc[2][8];
  #pragma unroll
  for (int mt = 0; mt < 2; ++mt)
    #pragma unroll
    for (int nt = 0; nt < 8; ++nt) acc[mt][nt] = (f32x4){0.f,0.f,0.f,0.f};

  for (int mc = 0; mc < 4; ++mc) {
    __syncthreads();
    #pragma unroll
    for (int ld2 = 0; ld2 < 4; ++ld2) {
      int flat = t + 256*ld2; int r = flat >> 3, g = flat & 7;
      *(short8*)(qs + r*72 + g*8) = *(const short8*)(qpg + (size_t)r*MM + mc*64 + g*8);
      *(short8*)(ks + r*72 + g*8) = *(const short8*)(kpg + (size_t)r*MM + mc*64 + g*8);
    }
    __syncthreads();
    #pragma unroll
    for (int kk = 0; kk < 2; ++kk) {
      short8 af0 = *(const short8*)(qs + (rt0*16 + ln)*72 + kk*32 + lq*8);
      short8 af1 = *(const short8*)(qs + (rt1*16 + ln)*72 + kk*32 + lq*8);
      #pragma unroll
      for (int nt = 0; nt < 8; ++nt) {
        if (nt <= rt1) {
          short8 bf = *(const short8*)(ks + (nt*16 + ln)*72 + kk*32 + lq*8);
          if (nt <= rt0) acc[0][nt] = MFMA(af0, bf, acc[0][nt]);
          acc[1][nt] = MFMA(af1, bf, acc[1][nt]);
        }
      }
    }
  }

  __syncthreads();

  ushort* P   = (ushort*)lds;             // [128][136]
  ushort* Vts = (ushort*)(lds + 34816);   // [64][136]

  float rs[2][4] = {{0,0,0,0},{0,0,0,0}};
  #pragma unroll
  for (int mt = 0; mt < 2; ++mt) {
    const int ibase = (mt ? rt1 : rt0) * 16;
    #pragma unroll
    for (int nt = 0; nt < 8; ++nt)
      #pragma unroll
      for (int reg = 0; reg < 4; ++reg) {
        int i = ibase + lq*4 + reg;
        int j = nt*16 + ln;
        float v = (j <= i) ? acc[mt][nt][reg] : 0.f;
        rs[mt][reg] += v;
        P[i*136 + j] = f2b(v);
      }
  }
  #pragma unroll
  for (int mt = 0; mt < 2; ++mt) {
    const int ibase = (mt ? rt1 : rt0) * 16;
    #pragma unroll
    for (int reg = 0; reg < 4; ++reg) {
      float s = rs[mt][reg];
      s += __shfl_xor(s, 1); s += __shfl_xor(s, 2);
      s += __shfl_xor(s, 4); s += __shfl_xor(s, 8);
      if (ln == 0) den_i[ibase + lq*4 + reg] = s;
    }
  }

  const ushort* vtg = (const ushort*)(ws + OFFB_VT) + (size_t)bh*DH*NN + tc*CHK;
  #pragma unroll
  for (int ld2 = 0; ld2 < 4; ++ld2) {
    int flat = t + 256*ld2; int e = flat >> 4, g = flat & 15;
    *(short8*)(Vts + e*136 + g*8) = *(const short8*)(vtg + (size_t)e*NN + g*8);
  }
  __syncthreads();

  {
    const float* zp = (const float*)(ws + OFFB_Z) + (size_t)blk*MM;
    const int r = t >> 1, hf = t & 1;
    const ushort* qrow = qpg + (size_t)r*MM + hf*128;
    float s = 0.f;
    #pragma unroll
    for (int g = 0; g < 16; ++g) {
      short8 qv = *(const short8*)(qrow + g*8);
      const float* zz = zp + hf*128 + g*8;
      #pragma unroll
      for (int x = 0; x < 8; ++x)
        s += b2f((ushort)qv[x]) * (zz[x] + EPSD);
    }
    s += __shfl_xor(s, 1);
    if (hf == 0) dinv_s[r] = 1.0f / (s + den_i[r]);
  }

  f32x4 oacc[2][4];
  #pragma unroll
  for (int mt = 0; mt < 2; ++mt)
    #pragma unroll
    for (int nt = 0; nt < 4; ++nt) oacc[mt][nt] = (f32x4){0.f,0.f,0.f,0.f};

  #pragma unroll
  for (int kk = 0; kk < 4; ++kk) {
    short8 af0 = *(const short8*)(P + (rt0*16 + ln)*136 + kk*32 + lq*8);
    short8 af1 = *(const short8*)(P + (rt1*16 + ln)*136 + kk*32 + lq*8);
    #pragma unroll
    for (int nt = 0; nt < 4; ++nt) {
      short8 bf = *(const short8*)(Vts + (nt*16 + ln)*136 + kk*32 + lq*8);
      oacc[0][nt] = MFMA(af0, bf, oacc[0][nt]);
      oacc[1][nt] = MFMA(af1, bf, oacc[1][nt]);
    }
  }
  __syncthreads();

  ushort* qs2 = (ushort*)lds;           // [128][72]
  ushort* ss  = qs2 + 128*72;           // [64][72]
  const ushort* spg = (const ushort*)(ws + OFFB_SP) + (size_t)blk*DH*MM;
  for (int mc = 0; mc < 4; ++mc) {
    if (mc) __syncthreads();
    #pragma unroll
    for (int ld2 = 0; ld2 < 4; ++ld2) {
      int flat = t + 256*ld2; int r = flat >> 3, g = flat & 7;
      *(short8*)(qs2 + r*72 + g*8) = *(const short8*)(qpg + (size_t)r*MM + mc*64 + g*8);
    }
    #pragma unroll
    for (int ld2 = 0; ld2 < 2; ++ld2) {
      int flat = t + 256*ld2; int e = flat >> 3, g = flat & 7;
      *(short8*)(ss + e*72 + g*8) = *(const short8*)(spg + (size_t)e*MM + mc*64 + g*8);
    }
    __syncthreads();
    #pragma unroll
    for (int kk = 0; kk < 2; ++kk) {
      short8 af0 = *(const short8*)(qs2 + (rt0*16 + ln)*72 + kk*32 + lq*8);
      short8 af1 = *(const short8*)(qs2 + (rt1*16 + ln)*72 + kk*32 + lq*8);
      #pragma unroll
      for (int nt = 0; nt < 4; ++nt) {
        short8 bf = *(const short8*)(ss + (nt*16 + ln)*72 + kk*32 + lq*8);
        oacc[0][nt] = MFMA(af0, bf, oacc[0][nt]);
        oacc[1][nt] = MFMA(af1, bf, oacc[1][nt]);
      }
    }
  }

  #pragma unroll
  for (int mt = 0; mt < 2; ++mt) {
    const int ibase = (mt ? rt1 : rt0) * 16;
    #pragma unroll
    for (int reg = 0; reg < 4; ++reg) {
      const int i = ibase + lq*4 + reg;
      const float di = dinv_s[i];
      float* dst = out + ((size_t)(b*NN) + tc*CHK + i)*DD + h*DH;
      #pragma unroll
      for (int nt = 0; nt < 4; ++nt)
        dst[nt*16 + ln] = oacc[mt][nt][reg] * di;
    }
  }
}

extern "C" void kernel_launch(void* const* d_in, const int* in_sizes, int n_in,
                              void* d_out, int out_size, void* d_ws, size_t ws_size,
                              hipStream_t stream) {
  (void)in_sizes; (void)n_in; (void)out_size; (void)ws_size;
  const float* q    = (const float*)d_in[0];
  const float* k    = (const float*)d_in[1];
  const float* v    = (const float*)d_in[2];
  const float* proj = (const float*)d_in[3];
  float* out = (float*)d_out;
  char*  ws  = (char*)d_ws;

  prep_kernel<<<16, 256, 0, stream>>>(proj, ws);
  mega_kernel<<<2560, 256, 0, stream>>>(q, k, v, ws);
  featm2_kernel<<<1024, 256, 0, stream>>>(k, ws);
  sprefix_kernel<<<512, 256, 0, stream>>>(ws);
  fused_kernel<<<512, 256, 0, stream>>>(out, ws);
}

// Round 9
// 187.888 us; speedup vs baseline: 4.0498x; 1.0167x over previous
//
#include <hip/hip_runtime.h>
#include <math.h>

#define BB 4
#define NN 2048
#define DD 512
#define HH 8
#define DH 64
#define MM 256
#define BH 32            // B*H
#define CHK 128
#define NCH 16           // N / CHK
#define ROWS (BH*NN)     // 65536

constexpr float NRM   = 0.35355339059327373f;  // 64^-0.25
constexpr float RATIO = 0.0625f;               // 256^-0.5
constexpr float EPSK  = 1e-4f;
constexpr float EPSD  = 1e-6f;
constexpr float REPS  = 0.0625f * 1e-4f;       // RATIO*EPSK

// ---------------- workspace byte offsets ----------------
// qp bf16 [row][m]; SP bf16; KP holds t = exp(dash-diag-m_blk) bf16;
// Vt bf16 [bh][e][n]; z fp32; kmp fp32[1024] per-block max; sfac fp32[1024];
// projb bf16[256][64]
#define OFFB_QP   ((size_t)0)
#define OFFB_SP   ((size_t)33554432)
#define OFFB_KP   (OFFB_SP + (size_t)16777216)
#define OFFB_VT   (OFFB_KP + (size_t)33554432)
#define OFFB_Z    (OFFB_VT + (size_t)8388608)
#define OFFB_KMP  (OFFB_Z  + (size_t)524288)
#define OFFB_SF   (OFFB_KMP + (size_t)4096)
#define OFFB_PJB  (OFFB_SF + (size_t)4096)

typedef __attribute__((ext_vector_type(8))) short short8;
typedef __attribute__((ext_vector_type(4))) float f32x4;

__device__ __forceinline__ float b2f(ushort u) {
  union { float f; unsigned int i; } x; x.i = ((unsigned int)u) << 16; return x.f;
}
__device__ __forceinline__ ushort f2b(float f) {  // RNE
  unsigned int u = __float_as_uint(f);
  unsigned int r = (u + 0x7FFFu + ((u >> 16) & 1u)) >> 16;
  return (ushort)r;
}

#define MFMA(a,b,c) __builtin_amdgcn_mfma_f32_16x16x32_bf16(a, b, c, 0, 0, 0)

// proj fp32 [256][64] -> bf16 (done once)
__global__ __launch_bounds__(256) void prep_kernel(const float* __restrict__ proj,
                                                   char* __restrict__ ws) {
  const int i = blockIdx.x*256 + threadIdx.x;     // 4096 threads x 4 elems
  float4 v = *(const float4*)(proj + (size_t)i*4);
  ushort4 o;
  o.x = f2b(v.x); o.y = f2b(v.y); o.z = f2b(v.z); o.w = f2b(v.w);
  *(ushort4*)((ushort*)(ws + OFFB_PJB) + (size_t)i*4) = o;
}

// ---------------------------------------------------------------------------
// Feature body. 64 rows/block, 256 features in two 128-halves.
// MODE 0 (Q): per-row max; qp = RATIO*(exp(dash-diag-rm)+EPSK) -> bf16
// MODE 1 (K): block max m_blk -> kmp[blk]; t = exp(dash-diag-m_blk) -> bf16
//             (consumers rescale by sfac = RATIO*exp(m_blk-km) and add REPS)
// ---------------------------------------------------------------------------
template<int MODE>
__device__ __forceinline__ void featm_body(const float* __restrict__ inp,
                                           const ushort* __restrict__ projb,
                                           char* __restrict__ ws,
                                           char* lds, int blk) {
  ushort* xh = (ushort*)lds;
  ushort* xl = xh + 64*72;
  ushort* ps = xl + 64*72;                 // [128][72]
  ushort* qt = (ushort*)lds;               // [64][264] (epilogue)
  float* diag_s = (float*)(lds + 36864);
  float (*wmax)[4] = (float(*)[4])(lds + 37120);
  float* kred = (float*)(lds + 38144);

  const int t  = threadIdx.x;
  const int w  = t >> 6;
  const int l  = t & 63;
  const int lq = l >> 4;
  const int ln = l & 15;

  const int rowbase = blk * 64;
  const int bh = rowbase >> 11;
  const int b  = bh >> 3, h = bh & 7;
  const int n0 = rowbase & (NN - 1);

  // ---- stage X (scaled, hi/lo split) + diag ----
  {
    const int r  = t >> 2;
    const int c0 = (t & 3) * 16;
    const float* src = inp + ((size_t)(b*NN + n0 + r))*DD + h*DH + c0;
    float vv[16];
    #pragma unroll
    for (int j = 0; j < 4; ++j) {
      float4 v = *(const float4*)(src + j*4);
      vv[4*j+0] = v.x*NRM; vv[4*j+1] = v.y*NRM;
      vv[4*j+2] = v.z*NRM; vv[4*j+3] = v.w*NRM;
    }
    float s = 0.f;
    ushort hi[16], lo[16];
    #pragma unroll
    for (int j = 0; j < 16; ++j) {
      s += vv[j]*vv[j];
      hi[j] = f2b(vv[j]);
      lo[j] = f2b(vv[j] - b2f(hi[j]));
    }
    *(short8*)(xh + r*72 + c0)     = *(short8*)&hi[0];
    *(short8*)(xh + r*72 + c0 + 8) = *(short8*)&hi[8];
    *(short8*)(xl + r*72 + c0)     = *(short8*)&lo[0];
    *(short8*)(xl + r*72 + c0 + 8) = *(short8*)&lo[8];
    s += __shfl_xor(s, 1); s += __shfl_xor(s, 2);
    if ((t & 3) == 0) diag_s[r] = 0.5f * s;
  }

  f32x4 acc[4][4];
  #pragma unroll
  for (int mt = 0; mt < 4; ++mt)
    #pragma unroll
    for (int c = 0; c < 4; ++c) acc[mt][c] = (f32x4){0.f,0.f,0.f,0.f};

  // ---- two proj halves: wave w covers features p*128 + w*32 + {0..31} ----
  #pragma unroll
  for (int p = 0; p < 2; ++p) {
    if (p) __syncthreads();
    #pragma unroll
    for (int ld = 0; ld < 4; ++ld) {
      int flat = t + 256*ld;              // < 1024 : 128 rows x 8 granules
      int r = flat >> 3, g = flat & 7;
      *(short8*)(ps + r*72 + g*8) = *(const short8*)(projb + (size_t)(p*128 + r)*DH + g*8);
    }
    __syncthreads();
    #pragma unroll
    for (int kk = 0; kk < 2; ++kk) {
      short8 ah[4], al[4];
      #pragma unroll
      for (int mt = 0; mt < 4; ++mt) {
        ah[mt] = *(const short8*)(xh + (mt*16 + ln)*72 + kk*32 + lq*8);
        al[mt] = *(const short8*)(xl + (mt*16 + ln)*72 + kk*32 + lq*8);
      }
      #pragma unroll
      for (int ntl = 0; ntl < 2; ++ntl) {
        short8 bf = *(const short8*)(ps + (w*32 + ntl*16 + ln)*72 + kk*32 + lq*8);
        #pragma unroll
        for (int mt = 0; mt < 4; ++mt) {
          acc[mt][2*p+ntl] = MFMA(al[mt], bf, acc[mt][2*p+ntl]);
          acc[mt][2*p+ntl] = MFMA(ah[mt], bf, acc[mt][2*p+ntl]);
        }
      }
    }
  }

  if (MODE == 0) {
    #pragma unroll
    for (int mt = 0; mt < 4; ++mt)
      #pragma unroll
      for (int reg = 0; reg < 4; ++reg) {
        float m = acc[mt][0][reg];
        #pragma unroll
        for (int c = 1; c < 4; ++c) m = fmaxf(m, acc[mt][c][reg]);
        m = fmaxf(m, __shfl_xor(m, 1));
        m = fmaxf(m, __shfl_xor(m, 2));
        m = fmaxf(m, __shfl_xor(m, 4));
        m = fmaxf(m, __shfl_xor(m, 8));
        if (ln == 0) wmax[mt*16 + lq*4 + reg][w] = m;
      }
  } else {
    // block max over raw dash
    float mx = -1e30f;
    #pragma unroll
    for (int mt = 0; mt < 4; ++mt)
      #pragma unroll
      for (int c = 0; c < 4; ++c)
        #pragma unroll
        for (int reg = 0; reg < 4; ++reg) mx = fmaxf(mx, acc[mt][c][reg]);
    #pragma unroll
    for (int m = 1; m < 64; m <<= 1) mx = fmaxf(mx, __shfl_xor(mx, m));
    if (l == 0) kred[w] = mx;
  }
  __syncthreads();   // wmax/kred ready; all ps/xh/xl reads done -> qt safe

  float km = 0.f;
  if (MODE == 1) {
    km = fmaxf(fmaxf(kred[0], kred[1]), fmaxf(kred[2], kred[3]));
    if (t == 0) ((float*)(ws + OFFB_KMP))[blk] = km;
  }

  #pragma unroll
  for (int mt = 0; mt < 4; ++mt)
    #pragma unroll
    for (int reg = 0; reg < 4; ++reg) {
      const int row = mt*16 + lq*4 + reg;
      float rm;
      if (MODE == 0) {
        float4 wm4 = *(const float4*)&wmax[row][0];
        rm = fmaxf(fmaxf(wm4.x, wm4.y), fmaxf(wm4.z, wm4.w));
      } else {
        rm = km;
      }
      const float dg = diag_s[row];
      #pragma unroll
      for (int c = 0; c < 4; ++c) {
        const int f = (c >> 1)*128 + w*32 + (c & 1)*16 + ln;
        const float e = __expf(acc[mt][c][reg] - dg - rm);
        qt[row*264 + f] = f2b(MODE == 0 ? RATIO*(e + EPSK) : e);
      }
    }
  __syncthreads();

  ushort* dstbase = (ushort*)(ws + (MODE == 0 ? OFFB_QP : OFFB_KP)) + (size_t)rowbase*MM;
  #pragma unroll
  for (int ld = 0; ld < 8; ++ld) {
    int flat = t + 256*ld;             // < 2048
    int row = flat >> 5, g = flat & 31;
    *(short8*)(dstbase + (size_t)row*MM + g*8) = *(const short8*)(qt + row*264 + g*8);
  }
}

// Vt[bh][e][n] = bf16(V[b][n][h*64+e])
__device__ __forceinline__ void vt_body(const float* __restrict__ value,
                                        char* __restrict__ ws,
                                        char* lds, int blk) {
  float (*vsh)[68] = (float(*)[68])lds;   // [128][68]
  const int t = threadIdx.x;
  const int bh = blk >> 4, nc = blk & 15;
  const int b = bh >> 3, h = bh & 7;
  const int n0 = nc * CHK;
  #pragma unroll
  for (int l = 0; l < 8; ++l) {
    int flat = t + 256*l;
    int r = flat >> 4, g = flat & 15;
    *(float4*)&vsh[r][g*4] = *(const float4*)(value + ((size_t)(b*NN + n0 + r))*DD + h*DH + g*4);
  }
  __syncthreads();
  const int e = t & 63, qd = t >> 6;
  ushort* vt = (ushort*)(ws + OFFB_VT) + ((size_t)bh*DH + e)*NN + n0 + qd*32;
  #pragma unroll
  for (int p = 0; p < 16; ++p) {
    unsigned int lo = f2b(vsh[qd*32 + 2*p][e]);
    unsigned int hi = f2b(vsh[qd*32 + 2*p + 1][e]);
    ((unsigned int*)vt)[p] = lo | (hi << 16);
  }
}

// mega: blocks [0,1024) featQ; [1024,2048) featK (t + m_blk); [2048,2560) V^T
__global__ __launch_bounds__(256) void mega_kernel(const float* __restrict__ q,
                                                   const float* __restrict__ k,
                                                   const float* __restrict__ v,
                                                   char* __restrict__ ws) {
  __shared__ __align__(16) char lds[38160];
  const ushort* projb = (const ushort*)(ws + OFFB_PJB);
  const int blk = blockIdx.x;
  if (blk < 1024)       featm_body<0>(q, projb, ws, lds, blk);
  else if (blk < 2048)  featm_body<1>(k, projb, ws, lds, blk - 1024);
  else                  vt_body(v, ws, lds, blk - 2048);
}

// sfac[blk] = RATIO * exp(m_blk - km[bh])
__global__ __launch_bounds__(256) void sfac_kernel(char* __restrict__ ws) {
  const int blk = blockIdx.x*256 + threadIdx.x;   // < 1024
  const int bh = blk >> 5;
  const float* kmp = (const float*)(ws + OFFB_KMP);
  float km = -1e30f;
  #pragma unroll
  for (int i = 0; i < 32; ++i) km = fmaxf(km, kmp[bh*32 + i]);
  ((float*)(ws + OFFB_SF))[blk] = RATIO * __expf(kmp[blk] - km);
}

// ---------------------------------------------------------------------------
// MFMA chunk-scan, 512 blocks (bh x 16-feature slice). kp rescale (t -> kp)
// is applied during kpT staging: kp = fmaf(t, sfac_row, REPS).
// ---------------------------------------------------------------------------
__global__ __launch_bounds__(256) void sprefix_kernel(char* __restrict__ ws) {
  __shared__ __align__(16) unsigned int kpTu[16*68];   // [m 16][seq-pair 64 +pad]
  __shared__ __align__(16) ushort Vts[64*136];         // [e 64][seq 128 +pad]
  __shared__ float zred[16][16];

  const int t  = threadIdx.x;
  const int w  = t >> 6;
  const int l  = t & 63;
  const int lq = l >> 4;
  const int ln = l & 15;
  const int bh = blockIdx.x >> 4;
  const int ms = blockIdx.x & 15;       // feature slice [ms*16, ms*16+16)

  const ushort* kpb = (const ushort*)(ws + OFFB_KP) + (size_t)bh*NN*MM + ms*16;
  const ushort* vtb = (const ushort*)(ws + OFFB_VT) + (size_t)bh*DH*NN;
  const float*  sf  = (const float*)(ws + OFFB_SF);
  ushort* spb = (ushort*)(ws + OFFB_SP) + (size_t)bh*NCH*DH*MM + ms*16;
  float*  zb  = (float*)(ws + OFFB_Z) + (size_t)bh*NCH*MM + ms*16;

  f32x4 acc = (f32x4){0.f,0.f,0.f,0.f};
  float zrun = 0.f;

  for (int tc = 0; tc < NCH; ++tc) {
    __syncthreads();

    if (t < 16) {
      if (tc > 0) {
        float s = 0.f;
        #pragma unroll
        for (int q = 0; q < 16; ++q) s += zred[q][t];
        zrun += s;
      }
      zb[(size_t)tc*MM + t] = zrun;
    }
    // dump exclusive S prefix (C-layout: row=e, col=m)
    {
      ushort* sp = spb + (size_t)tc*DH*MM;
      #pragma unroll
      for (int reg = 0; reg < 4; ++reg)
        sp[(size_t)(w*16 + lq*4 + reg)*MM + ln] = f2b(acc[reg]);
    }

    // stage kpT with rescale: kpTu[m][jp] = kp[2jp][m] | kp[2jp+1][m]<<16
    const ushort* kslice = kpb + (size_t)tc*CHK*MM;
    if (t < 128) {
      int jp = t >> 1, mo = t & 1;      // rows 2jp, 2jp+1 share the scale block
      float s0 = sf[bh*32 + tc*2 + (jp >> 5)];
      short8 a = *(const short8*)(kslice + (size_t)(2*jp)*MM + mo*8);
      short8 c = *(const short8*)(kslice + (size_t)(2*jp+1)*MM + mo*8);
      #pragma unroll
      for (int i = 0; i < 8; ++i) {
        ushort ua = f2b(fmaf(b2f((ushort)a[i]), s0, REPS));
        ushort uc = f2b(fmaf(b2f((ushort)c[i]), s0, REPS));
        kpTu[(mo*8 + i)*68 + jp] = (unsigned int)ua | ((unsigned int)uc << 16);
      }
    }
    // stage Vt chunk [64 e][128 seq]
    #pragma unroll
    for (int it = 0; it < 4; ++it) {
      int slot = t + 256*it;           // < 1024
      int e = slot >> 4, g = slot & 15;
      *(short8*)(Vts + e*136 + g*8) = *(const short8*)(vtb + (size_t)e*NN + tc*CHK + g*8);
    }
    __syncthreads();

    // z partials (consumed at next loop top)
    {
      int m = t & 15, q = t >> 4;
      float s = 0.f;
      #pragma unroll
      for (int u = 0; u < 4; ++u) {
        unsigned int p = kpTu[m*68 + q*4 + u];
        s += b2f((ushort)(p & 0xFFFF)) + b2f((ushort)(p >> 16));
      }
      zred[q][m] = s;
    }

    // MFMA: D[e][m] += sum_k Vt[e][k] * kpT[m][k]; wave w owns e-tile w
    #pragma unroll
    for (int kk = 0; kk < 4; ++kk) {
      short8 af = *(const short8*)(Vts + (w*16 + ln)*136 + kk*32 + lq*8);
      short8 bf = *(const short8*)((const ushort*)kpTu + (size_t)ln*136 + kk*32 + lq*8);
      acc = MFMA(af, bf, acc);
    }
  }
}

// ---------------------------------------------------------------------------
// Fused per-chunk kernel: merged K-loop does BOTH Sc = Qp Kp^T (balanced
// lower-tri tiles, wave w owns row-tiles {w, 7-w}) AND oacc += Qp @ S_prev,
// sharing one qp staging. Then mask/rowsum/P, den, P@V, epilogue.
// kp rescale applied during ks staging.
// NOTE: __syncthreads() after the den block is REQUIRED — epilogue reads
// dinv_s rows written by other waves (R8 race: removing phase C removed the
// barrier that used to order this).
// ---------------------------------------------------------------------------
__global__ __launch_bounds__(256) void fused_kernel(float* __restrict__ out,
                                                    char* __restrict__ ws) {
  __shared__ __align__(16) char lds[52224];
  __shared__ float den_i[128];
  __shared__ float dinv_s[128];

  const int t  = threadIdx.x;
  const int w  = t >> 6;
  const int l  = t & 63;
  const int lq = l >> 4;
  const int ln = l & 15;
  const int rt0 = w;          // row-tile A
  const int rt1 = 7 - w;      // row-tile B  (rt0 < rt1)
  const int blk = blockIdx.x;
  const int bh = blk >> 4, tc = blk & 15;
  const int b = bh >> 3, h = bh & 7;
  const size_t rowbase = (size_t)bh*NN + tc*CHK;

  const ushort* qpg = (const ushort*)(ws + OFFB_QP) + rowbase*MM;
  const ushort* kpg = (const ushort*)(ws + OFFB_KP) + rowbase*MM;
  const ushort* spg = (const ushort*)(ws + OFFB_SP) + (size_t)blk*DH*MM;
  const float*  sf  = (const float*)(ws + OFFB_SF);
  const float sc0 = sf[blk*2], sc1 = sf[blk*2 + 1];

  ushort* qs = (ushort*)lds;            // [128][72] 18432 B
  ushort* ks = qs + 128*72;             // [128][72] 18432 B
  ushort* ss = ks + 128*72;             // [64][72]   9216 B  (total 46080)

  f32x4 acc[2][8];
  #pragma unroll
  for (int mt = 0; mt < 2; ++mt)
    #pragma unroll
    for (int nt = 0; nt < 8; ++nt) acc[mt][nt] = (f32x4){0.f,0.f,0.f,0.f};
  f32x4 oacc[2][4];
  #pragma unroll
  for (int mt = 0; mt < 2; ++mt)
    #pragma unroll
    for (int nt = 0; nt < 4; ++nt) oacc[mt][nt] = (f32x4){0.f,0.f,0.f,0.f};

  // ---- merged K-loop: Sc (Qp Kp^T) + oacc (Qp S_prev), K=256 in 4x64 ----
  for (int mc = 0; mc < 4; ++mc) {
    __syncthreads();
    #pragma unroll
    for (int ld2 = 0; ld2 < 4; ++ld2) {
      int flat = t + 256*ld2; int r = flat >> 3, g = flat & 7;
      *(short8*)(qs + r*72 + g*8) = *(const short8*)(qpg + (size_t)r*MM + mc*64 + g*8);
    }
    #pragma unroll
    for (int ld2 = 0; ld2 < 4; ++ld2) {
      int flat = t + 256*ld2; int r = flat >> 3, g = flat & 7;
      short8 kv = *(const short8*)(kpg + (size_t)r*MM + mc*64 + g*8);
      const float sc = (r & 64) ? sc1 : sc0;
      ushort ov[8];
      #pragma unroll
      for (int i = 0; i < 8; ++i) ov[i] = f2b(fmaf(b2f((ushort)kv[i]), sc, REPS));
      *(short8*)(ks + r*72 + g*8) = *(short8*)&ov[0];
    }
    #pragma unroll
    for (int ld2 = 0; ld2 < 2; ++ld2) {
      int flat = t + 256*ld2; int e = flat >> 3, g = flat & 7;
      *(short8*)(ss + e*72 + g*8) = *(const short8*)(spg + (size_t)e*MM + mc*64 + g*8);
    }
    __syncthreads();
    #pragma unroll
    for (int kk = 0; kk < 2; ++kk) {
      short8 af0 = *(const short8*)(qs + (rt0*16 + ln)*72 + kk*32 + lq*8);
      short8 af1 = *(const short8*)(qs + (rt1*16 + ln)*72 + kk*32 + lq*8);
      #pragma unroll
      for (int nt = 0; nt < 8; ++nt) {
        if (nt <= rt1) {
          short8 bf = *(const short8*)(ks + (nt*16 + ln)*72 + kk*32 + lq*8);
          if (nt <= rt0) acc[0][nt] = MFMA(af0, bf, acc[0][nt]);
          acc[1][nt] = MFMA(af1, bf, acc[1][nt]);
        }
      }
      #pragma unroll
      for (int nt = 0; nt < 4; ++nt) {
        short8 bf = *(const short8*)(ss + (nt*16 + ln)*72 + kk*32 + lq*8);
        oacc[0][nt] = MFMA(af0, bf, oacc[0][nt]);
        oacc[1][nt] = MFMA(af1, bf, oacc[1][nt]);
      }
    }
  }

  __syncthreads();   // qs/ks/ss dead -> P + Vts region

  ushort* P   = (ushort*)lds;             // [128][136]
  ushort* Vts = (ushort*)(lds + 34816);   // [64][136]

  float rs[2][4] = {{0,0,0,0},{0,0,0,0}};
  #pragma unroll
  for (int mt = 0; mt < 2; ++mt) {
    const int ibase = (mt ? rt1 : rt0) * 16;
    #pragma unroll
    for (int nt = 0; nt < 8; ++nt)
      #pragma unroll
      for (int reg = 0; reg < 4; ++reg) {
        int i = ibase + lq*4 + reg;
        int j = nt*16 + ln;
        float v = (j <= i) ? acc[mt][nt][reg] : 0.f;
        rs[mt][reg] += v;
        P[i*136 + j] = f2b(v);
      }
  }
  #pragma unroll
  for (int mt = 0; mt < 2; ++mt) {
    const int ibase = (mt ? rt1 : rt0) * 16;
    #pragma unroll
    for (int reg = 0; reg < 4; ++reg) {
      float s = rs[mt][reg];
      s += __shfl_xor(s, 1); s += __shfl_xor(s, 2);
      s += __shfl_xor(s, 4); s += __shfl_xor(s, 8);
      if (ln == 0) den_i[ibase + lq*4 + reg] = s;
    }
  }

  const ushort* vtg = (const ushort*)(ws + OFFB_VT) + (size_t)bh*DH*NN + tc*CHK;
  #pragma unroll
  for (int ld2 = 0; ld2 < 4; ++ld2) {
    int flat = t + 256*ld2; int e = flat >> 4, g = flat & 15;
    *(short8*)(Vts + e*136 + g*8) = *(const short8*)(vtg + (size_t)e*NN + g*8);
  }
  __syncthreads();

  {
    const float* zp = (const float*)(ws + OFFB_Z) + (size_t)blk*MM;
    const int r = t >> 1, hf = t & 1;
    const ushort* qrow = qpg + (size_t)r*MM + hf*128;
    float s = 0.f;
    #pragma unroll
    for (int g = 0; g < 16; ++g) {
      short8 qv = *(const short8*)(qrow + g*8);
      const float* zz = zp + hf*128 + g*8;
      #pragma unroll
      for (int x = 0; x < 8; ++x)
        s += b2f((ushort)qv[x]) * (zz[x] + EPSD);
    }
    s += __shfl_xor(s, 1);
    if (hf == 0) dinv_s[r] = 1.0f / (s + den_i[r]);
  }
  __syncthreads();   // dinv_s visible to all waves before the epilogue

  // ---- oacc += P @ V  (K=128) ----
  #pragma unroll
  for (int kk = 0; kk < 4; ++kk) {
    short8 af0 = *(const short8*)(P + (rt0*16 + ln)*136 + kk*32 + lq*8);
    short8 af1 = *(const short8*)(P + (rt1*16 + ln)*136 + kk*32 + lq*8);
    #pragma unroll
    for (int nt = 0; nt < 4; ++nt) {
      short8 bf = *(const short8*)(Vts + (nt*16 + ln)*136 + kk*32 + lq*8);
      oacc[0][nt] = MFMA(af0, bf, oacc[0][nt]);
      oacc[1][nt] = MFMA(af1, bf, oacc[1][nt]);
    }
  }

  #pragma unroll
  for (int mt = 0; mt < 2; ++mt) {
    const int ibase = (mt ? rt1 : rt0) * 16;
    #pragma unroll
    for (int reg = 0; reg < 4; ++reg) {
      const int i = ibase + lq*4 + reg;
      const float di = dinv_s[i];
      float* dst = out + ((size_t)(b*NN) + tc*CHK + i)*DD + h*DH;
      #pragma unroll
      for (int nt = 0; nt < 4; ++nt)
        dst[nt*16 + ln] = oacc[mt][nt][reg] * di;
    }
  }
}

extern "C" void kernel_launch(void* const* d_in, const int* in_sizes, int n_in,
                              void* d_out, int out_size, void* d_ws, size_t ws_size,
                              hipStream_t stream) {
  (void)in_sizes; (void)n_in; (void)out_size; (void)ws_size;
  const float* q    = (const float*)d_in[0];
  const float* k    = (const float*)d_in[1];
  const float* v    = (const float*)d_in[2];
  const float* proj = (const float*)d_in[3];
  float* out = (float*)d_out;
  char*  ws  = (char*)d_ws;

  prep_kernel<<<16, 256, 0, stream>>>(proj, ws);
  mega_kernel<<<2560, 256, 0, stream>>>(q, k, v, ws);
  sfac_kernel<<<4, 256, 0, stream>>>(ws);
  sprefix_kernel<<<512, 256, 0, stream>>>(ws);
  fused_kernel<<<512, 256, 0, stream>>>(out, ws);
}